// Round 15
// baseline (603.016 us; speedup 1.0000x reference)
//
#include <hip/hip_runtime.h>
#include <math.h>

#define NNODES 32768
#define NLIG   1024
#define KAT    32
#define KNN    8
#define NEDGES (NNODES*KNN)
#define HID    128
#define TF     16
#define NG     20
#define OUTF   64

#define NPB    16           // nodes per edge-block
#define EPB    128          // edges per edge-block
#define K1     320          // padded GEMM1 K (292 -> 320)
#define MIDSTR 132          // node_k sMid row stride (floats)

typedef unsigned short u16;
typedef _Float16 f16;
typedef __attribute__((__ext_vector_type__(8))) _Float16 f16x8;
typedef __attribute__((__ext_vector_type__(4))) float f32x4;

union U8h { f16 a[8]; f16x8 v; };

// Gaussian smearing constants: og[g] = 5^(g/19)-1, coeff = -0.5/diff^2
__device__ const float GS_OG[20] = {
    0.0f, 0.0883984f, 0.1845966f, 0.2893285f, 0.4033028f,
    0.5273539f, 0.6623701f, 0.8093209f, 0.9692606f, 1.1433389f,
    1.3328075f, 1.5390240f, 1.7634662f, 2.0077560f, 2.2736369f,
    2.5630207f, 2.8779861f, 3.2207938f, 3.5939058f, 4.0f };
__device__ const float GS_CF[20] = {
    -63.9853f, -63.9853f, -54.0303f, -45.5840f, -38.4908f,
    -32.4913f, -27.4283f, -23.1540f, -19.5460f, -16.4999f,
    -13.9282f, -11.7577f, -9.92569f, -8.37837f, -7.07287f,
    -5.97065f, -5.04016f, -4.25470f, -3.59163f, -3.03191f };

__device__ __forceinline__ float siluf(float v) {
    return __fdividef(v, 1.0f + __expf(-v));
}
__device__ __forceinline__ float sigf(float v) {
    return __fdividef(1.0f, 1.0f + __expf(-v));
}
__device__ __forceinline__ f32x4 mfma16(f16x8 a, f16x8 b, f32x4 c) {
    return __builtin_amdgcn_mfma_f32_16x16x32_f16(a, b, c, 0, 0, 0);
}

// ---------------------------------------------------------------- prep (fp16 single)
#define PREP_TEMB 16000
#define PREP_W1   (4*128*K1)       // 163840
#define PREP_W2   (4*128*128)      // 65536
#define PREP_WN1  (4*128*256)      // 131072
#define PREP_WN2  (4*128*128)      // 65536
#define PREP_TOT  (PREP_TEMB+PREP_W1+PREP_W2+PREP_WN1+PREP_WN2)

__global__ __launch_bounds__(256) void prep_k(
    const float* __restrict__ temb, const float* __restrict__ We1,
    const float* __restrict__ We2,  const float* __restrict__ Wn1,
    const float* __restrict__ Wn2,
    f16* __restrict__ tembF,
    f16* __restrict__ W1T, f16* __restrict__ W2T,
    f16* __restrict__ WN1T, f16* __restrict__ WN2T)
{
    int i = blockIdx.x*256 + threadIdx.x;
    if (i >= PREP_TOT) return;
    float v; f16* dst; int di;
    if (i < PREP_TEMB) {
        v = temb[i]; dst = tembF; di = i;
    } else if (i < PREP_TEMB + PREP_W1) {
        int j = i - PREP_TEMB; di = j; dst = W1T;
        int l = j / (128*K1); int r = j - l*(128*K1);
        int col = r / K1, k = r - col*K1;
        v = (k < 292) ? We1[(size_t)l*292*128 + (size_t)k*128 + col] : 0.0f;
    } else if (i < PREP_TEMB + PREP_W1 + PREP_W2) {
        int j = i - PREP_TEMB - PREP_W1; di = j; dst = W2T;
        int l = j >> 14; int r = j & 16383;
        int col = r >> 7, k = r & 127;
        v = We2[(size_t)l*16384 + (size_t)k*128 + col];
    } else if (i < PREP_TEMB + PREP_W1 + PREP_W2 + PREP_WN1) {
        int j = i - PREP_TEMB - PREP_W1 - PREP_W2; di = j; dst = WN1T;
        int l = j >> 15; int r = j & 32767;
        int col = r >> 8, k = r & 255;
        v = Wn1[(size_t)l*32768 + (size_t)k*128 + col];
    } else {
        int j = i - PREP_TEMB - PREP_W1 - PREP_W2 - PREP_WN1; di = j; dst = WN2T;
        int l = j >> 14; int r = j & 16383;
        int col = r >> 7, k = r & 127;
        v = Wn2[(size_t)l*16384 + (size_t)k*128 + col];
    }
    dst[di] = (f16)v;
}

// ---------------------------------------------------------------- embed (8 nodes/block)
__global__ __launch_bounds__(256) void embed_k(
    const float* __restrict__ h, const int* __restrict__ t,
    const float* __restrict__ temb, const float* __restrict__ Win,
    const float* __restrict__ bin, float* __restrict__ hh,
    f16* __restrict__ hhF)
{
    __shared__ float sIn[8][32];
    const int tid = threadIdx.x;
    {
        const int n = tid >> 5, i = tid & 31;
        const int node = blockIdx.x*8 + n;
        sIn[n][i] = (i < TF) ? h[node*TF + i] : temb[t[node]*TF + (i-TF)];
    }
    __syncthreads();
    const int sub = tid >> 7, col = tid & 127;
    float acc[4];
    const float b = bin[col];
    acc[0]=acc[1]=acc[2]=acc[3]=b;
    #pragma unroll 8
    for (int i = 0; i < 32; ++i) {
        const float wv = Win[i*HID + col];
        acc[0] = fmaf(sIn[sub][i],   wv, acc[0]);
        acc[1] = fmaf(sIn[2+sub][i], wv, acc[1]);
        acc[2] = fmaf(sIn[4+sub][i], wv, acc[2]);
        acc[3] = fmaf(sIn[6+sub][i], wv, acc[3]);
    }
    #pragma unroll
    for (int nn = 0; nn < 4; ++nn) {
        const size_t idx = (size_t)(blockIdx.x*8 + nn*2 + sub)*HID + col;
        hh[idx] = acc[nn];
        hhF[idx] = (f16)acc[nn];
    }
}

// ---------------------------------------------------------------- edge
// M=128, 512 threads (8 waves), ONE column per thread. fp16 MFMA.
// Per-thread work halved vs the 256-thread version: acc[8] (32 AGPR),
// half the shuffles/SiLU, ~100 regs -> spill-free at (512,4) = 16 waves/CU.
__global__ __launch_bounds__(512, 4) void edge_k(
    const f16* __restrict__ hhF, const float* __restrict__ x,
    const int* __restrict__ ecol, const int* __restrict__ tbond,
    const f16* __restrict__ tembF,
    const f16* __restrict__ W1T, const f16* __restrict__ W2T,
    const float* __restrict__ be1, const float* __restrict__ g1,
    const float* __restrict__ bt1, const float* __restrict__ be2,
    const float* __restrict__ Watt, const float* __restrict__ batt,
    f16* __restrict__ aggF)
{
    // LDS (46592 B):
    //  [0,8192)       tbl (32 x 128 f16)       | after LN: sB2 (128x128 f16) [0,32768)
    //  [8192,24576)   tailB (128 x 64 f16)     | (sB2 tail)
    //  [32768,40960)  sStats (128 rows x 8 waves x float2)
    //  [40960,41984)  sMuInv (128 x f32x2)
    //  [41984,46080)  sAP (8 waves x 128 rows f32)
    //  [46080,46592)  sAttv (128 f32)
    __shared__ __align__(16) char smem[46592];
    f16*   tbl   = (f16*)(smem);
    f16*   tailB = (f16*)(smem + 8192);
    float* sStats= (float*)(smem + 32768);
    float* sMuInv= (float*)(smem + 40960);
    float* sAP   = (float*)(smem + 41984);
    float* sAttv = (float*)(smem + 46080);
    f16*   sB2   = (f16*)(smem);

    const int tid = threadIdx.x;
    const int node0 = blockIdx.x * NPB;
    const int ligBase = node0 & ~31;
    const int aBase   = node0 & 31;      // 0 or 16
    const int w = tid >> 6, lane = tid & 63, lr = lane & 15, lh = lane >> 4;
    const int colB = w*16 + lr;          // one column per thread

    // ---- per-lane col atom ids, packed 8x8b into 2 u32 -----------------
    unsigned aColPk0 = 0, aColPk1 = 0;
    #pragma unroll
    for (int rt = 0; rt < 4; ++rt)
        aColPk0 |= (unsigned)(ecol[node0*KNN + rt*16 + lr] & 31) << (rt*8);
    #pragma unroll
    for (int rt = 0; rt < 4; ++rt)
        aColPk1 |= (unsigned)(ecol[node0*KNN + (4+rt)*16 + lr] & 31) << (rt*8);

    // ---- GEMM1 weight pointer + first fragment -------------------------
    const f16* bF = W1T + (size_t)colB*K1 + lh*8;
    f16x8 wf = *(const f16x8*)bF;

    // ---- stage ligand hh table (32 atoms x 16 chunks; 512 writes) ------
    {
        const int a = tid >> 4, c4 = tid & 15;
        const f16x8 v = *(const f16x8*)(hhF + (size_t)(ligBase + a)*HID + c4*8);
        *(f16x8*)&tbl[a*128 + ((c4 ^ (a & 15)) << 3)] = v;
    }

    // ---- tail (fp16) [128 rows][8 chunks]: temb(2)|smear(3)|0(3) -------
    for (int pe = tid; pe < 1024; pe += 512) {
        const int row = pe & 127, part = pe >> 7;
        U8h vh;
        if (part < 2) {
            const int r = node0 + (row >> 3);
            const int c = ecol[node0*KNN + row];
            int sbi = r*(KAT-1) + c - (r/KAT)*KAT - (r < c ? 1 : 0);
            const int tb = tbond[sbi];
            #pragma unroll
            for (int j = 0; j < 8; ++j)
                vh.a[j] = tembF[tb*TF + part*8 + j];
        } else if (part < 5) {
            const int r = node0 + (row >> 3);
            const int c = ecol[node0*KNN + row];
            float dx = x[3*r]-x[3*c], dy = x[3*r+1]-x[3*c+1], dz = x[3*r+2]-x[3*c+2];
            float dist = fminf(sqrtf(dx*dx+dy*dy+dz*dz), 4.0f);
            #pragma unroll
            for (int j = 0; j < 8; ++j) {
                int g = (part-2)*8 + j;
                float v = 0.0f;
                if (g < NG) {
                    float dd = dist - GS_OG[g];
                    v = __expf(GS_CF[g]*dd*dd);
                }
                vh.a[j] = (f16)v;
            }
        } else {
            #pragma unroll
            for (int j = 0; j < 8; ++j) vh.a[j] = (f16)0.0f;
        }
        *(f16x8*)&tailB[row*64 + ((part ^ (row & 7)) << 3)] = vh.v;
    }
    __syncthreads();                                    // bar1

    // ---- GEMM1: [128 x 320] @ [320 x 128], 1-deep W prefetch -----------
    f32x4 acc[8];
    #pragma unroll
    for (int rt = 0; rt < 8; ++rt) acc[rt] = (f32x4){0,0,0,0};
    {
        #pragma unroll
        for (int s = 0; s < 10; ++s) {
            f16x8 nf = wf;
            if (s < 9) nf = *(const f16x8*)(bF + 32*(s+1));
            if (s < 4) {
                #pragma unroll
                for (int rt = 0; rt < 8; ++rt) {
                    const int aR = aBase + 2*rt + (lr >> 3);
                    const int c4 = s*4 + lh;
                    const int ad = aR*128 + ((c4 ^ (aR & 15)) << 3);
                    acc[rt] = mfma16(*(const f16x8*)&tbl[ad], wf, acc[rt]);
                }
            } else if (s < 8) {
                #pragma unroll
                for (int rt = 0; rt < 8; ++rt) {
                    const int aC = (int)((rt < 4 ? (aColPk0 >> (rt*8))
                                                 : (aColPk1 >> ((rt-4)*8))) & 31u);
                    const int c4 = (s-4)*4 + lh;
                    const int ad = aC*128 + ((c4 ^ (aC & 15)) << 3);
                    acc[rt] = mfma16(*(const f16x8*)&tbl[ad], wf, acc[rt]);
                }
            } else {
                #pragma unroll
                for (int rt = 0; rt < 8; ++rt) {
                    const int r = rt*16 + lr;
                    const int c = (s-8)*4 + lh;
                    const int ad = r*64 + ((c ^ (r & 7)) << 3);
                    acc[rt] = mfma16(*(const f16x8*)&tailB[ad], wf, acc[rt]);
                }
            }
            wf = nf;
        }
    }

    // ---- bias + per-wave LN partial reduce (over 16 lanes) -------------
    {
        const float b1 = be1[colB];
        #pragma unroll
        for (int rt = 0; rt < 8; ++rt) {
            float sv[4], qv[4];
            #pragma unroll
            for (int j = 0; j < 4; ++j) {
                const float a0 = acc[rt][j] + b1;
                acc[rt][j] = a0;
                sv[j] = a0; qv[j] = a0*a0;
            }
            #pragma unroll
            for (int msk = 1; msk < 16; msk <<= 1) {
                #pragma unroll
                for (int j = 0; j < 4; ++j) {
                    sv[j] += __shfl_xor(sv[j], msk);
                    qv[j] += __shfl_xor(qv[j], msk);
                }
            }
            if (lr == 0) {
                #pragma unroll
                for (int j = 0; j < 4; ++j) {
                    const int row = rt*16 + 4*lh + j;
                    sStats[(row*8 + w)*2 + 0] = sv[j];
                    sStats[(row*8 + w)*2 + 1] = qv[j];
                }
            }
        }
    }
    __syncthreads();                                    // bar2

    if (tid < EPB) {
        const float* rp = &sStats[tid*16];
        float s = 0.0f, q = 0.0f;
        #pragma unroll
        for (int k = 0; k < 8; ++k) {
            const float2 v = *(const float2*)&rp[2*k];
            s += v.x; q += v.y;
        }
        const float mu  = s * (1.0f/HID);
        const float var = q * (1.0f/HID) - mu*mu;
        sMuInv[tid*2 + 0] = mu;
        sMuInv[tid*2 + 1] = rsqrtf(var + 1e-5f);
    }
    __syncthreads();                                    // bar3

    // ---- GEMM2 weight pointer + first fragment -------------------------
    const f16* c2F = W2T + (size_t)colB*HID + lh*8;
    f16x8 g2f = *(const f16x8*)c2F;

    // ---- normalize + SiLU in regs, write fp16 acts to sB2 --------------
    {
        const float G = g1[colB], B = bt1[colB];
        const int gch = colB >> 3, cw = colB & 7;
        #pragma unroll
        for (int rt = 0; rt < 8; ++rt) {
            const int r0 = rt*16 + 4*lh;
            const float4 mi0 = *(const float4*)&sMuInv[r0*2];      // mu0,inv0,mu1,inv1
            const float4 mi1 = *(const float4*)&sMuInv[r0*2 + 4];  // mu2,inv2,mu3,inv3
            acc[rt][0] = siluf(fmaf((acc[rt][0]-mi0.x)*mi0.y, G, B));
            acc[rt][1] = siluf(fmaf((acc[rt][1]-mi0.z)*mi0.w, G, B));
            acc[rt][2] = siluf(fmaf((acc[rt][2]-mi1.x)*mi1.y, G, B));
            acc[rt][3] = siluf(fmaf((acc[rt][3]-mi1.z)*mi1.w, G, B));
            #pragma unroll
            for (int j = 0; j < 4; ++j) {
                const int row = r0 + j;
                sB2[row*128 + ((gch ^ (row & 15)) << 3) + cw] = (f16)acc[rt][j];
            }
        }
    }
    __syncthreads();                                    // bar4

    // ---- GEMM2: [128 x 128] @ [128 x 128] ------------------------------
    f32x4 d[8];
    #pragma unroll
    for (int rt = 0; rt < 8; ++rt) d[rt] = (f32x4){0,0,0,0};
    {
        #pragma unroll
        for (int s = 0; s < 4; ++s) {
            f16x8 nf = g2f;
            if (s < 3) nf = *(const f16x8*)(c2F + 32*(s+1));
            #pragma unroll
            for (int rt = 0; rt < 8; ++rt) {
                const int rowL = rt*16 + lr;
                const int c4 = s*4 + lh;
                const f16x8 ah = *(const f16x8*)&sB2[rowL*128 + ((c4 ^ (rowL & 15)) << 3)];
                d[rt] = mfma16(ah, g2f, d[rt]);
            }
            g2f = nf;
        }
    }

    // ---- SiLU in place + per-wave gate reduce --------------------------
    {
        const float b2 = be2[colB];
        #pragma unroll
        for (int rt = 0; rt < 8; ++rt)
            #pragma unroll
            for (int j = 0; j < 4; ++j)
                d[rt][j] = siluf(d[rt][j] + b2);
    }
    {
        const float wa = Watt[colB];
        #pragma unroll
        for (int rt = 0; rt < 8; ++rt) {
            float pa[4];
            #pragma unroll
            for (int j = 0; j < 4; ++j) pa[j] = d[rt][j]*wa;
            #pragma unroll
            for (int msk = 1; msk < 16; msk <<= 1) {
                #pragma unroll
                for (int j = 0; j < 4; ++j)
                    pa[j] += __shfl_xor(pa[j], msk);
            }
            if (lr == 0) {
                #pragma unroll
                for (int j = 0; j < 4; ++j)
                    sAP[w*128 + rt*16 + 4*lh + j] = pa[j];
            }
        }
    }
    __syncthreads();                                    // bar5
    if (tid < EPB) {
        float p = batt[0];
        #pragma unroll
        for (int k = 0; k < 8; ++k) p += sAP[k*128 + tid];
        sAttv[tid] = sigf(p);
    }
    __syncthreads();                                    // bar6

    // ---- gated aggregate -> aggF ---------------------------------------
    #pragma unroll
    for (int rt = 0; rt < 8; ++rt) {
        float s0 = 0.0f;
        #pragma unroll
        for (int j = 0; j < 4; ++j)
            s0 += d[rt][j] * sAttv[rt*16 + 4*lh + j];
        s0 += __shfl_xor(s0, 16);                       // lh pairs 0+1 / 2+3
        if ((lh & 1) == 0) {
            const int node = node0 + 2*rt + (lh >> 1);
            aggF[(size_t)node*HID + colB] = (f16)(s0*0.2f);
        }
    }
}

// ---------------------------------------------------------------- node (fp16 MFMA, 32 nodes/block)
__global__ __launch_bounds__(256, 6) void node_k(
    float* __restrict__ hh, f16* __restrict__ hhF,
    const f16* __restrict__ aggF,
    const f16* __restrict__ B1T, const f16* __restrict__ B2T,
    const float* __restrict__ bn1, const float* __restrict__ g2,
    const float* __restrict__ bt2, const float* __restrict__ bn2)
{
    __shared__ __align__(16) char smem[16896];
    float* sMid = (float*)smem;
    f16* sY = (f16*)smem;                // fp16 post-LN acts (8 KB)

    const int tid = threadIdx.x;
    const int node0 = blockIdx.x * 32;
    const int w = tid >> 6, lane = tid & 63, lr = lane & 15, lh = lane >> 4;
    const int colB0 = w*32 + lr, colB1 = colB0 + 16;

    const f16* a1f = hhF  + (size_t)(node0+lr)*HID + lh*8;
    const f16* a2f = aggF + (size_t)(node0+lr)*HID + lh*8;
    const f16* c1F0 = B1T + (size_t)colB0*256 + lh*8;
    const f16* c1F1 = B1T + (size_t)colB1*256 + lh*8;

    f32x4 acc00={0,0,0,0}, acc01={0,0,0,0}, acc10={0,0,0,0}, acc11={0,0,0,0};
    {
        f16x8 wf0 = *(const f16x8*)c1F0, wf1 = *(const f16x8*)c1F1;
        #pragma unroll
        for (int s = 0; s < 8; ++s) {
            f16x8 nf0 = wf0, nf1 = wf1;
            if (s < 7) {
                nf0 = *(const f16x8*)(c1F0 + 32*(s+1));
                nf1 = *(const f16x8*)(c1F1 + 32*(s+1));
            }
            f16x8 ah0, ah1;
            if (s < 4) {
                ah0 = *(const f16x8*)(a1f + 32*s);
                ah1 = *(const f16x8*)(a1f + 16*HID + 32*s);
            } else {
                ah0 = *(const f16x8*)(a2f + 32*(s-4));
                ah1 = *(const f16x8*)(a2f + 16*HID + 32*(s-4));
            }
            acc00 = mfma16(ah0, wf0, acc00);
            acc01 = mfma16(ah0, wf1, acc01);
            acc10 = mfma16(ah1, wf0, acc10);
            acc11 = mfma16(ah1, wf1, acc11);
            wf0 = nf0; wf1 = nf1;
        }
    }
    {
        const float b10 = bn1[colB0], b11 = bn1[colB1];
        #pragma unroll
        for (int j = 0; j < 4; ++j) {
            const int r0 = 4*lh + j;
            sMid[r0*MIDSTR + colB0]      = acc00[j] + b10;
            sMid[r0*MIDSTR + colB1]      = acc01[j] + b11;
            sMid[(16+r0)*MIDSTR + colB0] = acc10[j] + b10;
            sMid[(16+r0)*MIDSTR + colB1] = acc11[j] + b11;
        }
    }
    __syncthreads();

    float y[16];
    const int eLN = tid >> 3, c0 = (tid & 7)*16;
    {
        const float* mrow = &sMid[eLN*MIDSTR + c0];
        float4 v0 = *(const float4*)&mrow[0];
        float4 v1 = *(const float4*)&mrow[4];
        float4 v2 = *(const float4*)&mrow[8];
        float4 v3 = *(const float4*)&mrow[12];
        float s = v0.x+v0.y+v0.z+v0.w + v1.x+v1.y+v1.z+v1.w
                + v2.x+v2.y+v2.z+v2.w + v3.x+v3.y+v3.z+v3.w;
        float q = v0.x*v0.x+v0.y*v0.y+v0.z*v0.z+v0.w*v0.w
                + v1.x*v1.x+v1.y*v1.y+v1.z*v1.z+v1.w*v1.w
                + v2.x*v2.x+v2.y*v2.y+v2.z*v2.z+v2.w*v2.w
                + v3.x*v3.x+v3.y*v3.y+v3.z*v3.z+v3.w*v3.w;
        #pragma unroll
        for (int m = 4; m >= 1; m >>= 1) { s += __shfl_xor(s, m); q += __shfl_xor(q, m); }
        float mu  = s * (1.0f/HID);
        float var = q * (1.0f/HID) - mu*mu;
        float inv = rsqrtf(var + 1e-5f);
        const float4 G0 = *(const float4*)&g2[c0+0],  G1v = *(const float4*)&g2[c0+4];
        const float4 G2 = *(const float4*)&g2[c0+8],  G3 = *(const float4*)&g2[c0+12];
        const float4 B0 = *(const float4*)&bt2[c0+0], B1 = *(const float4*)&bt2[c0+4];
        const float4 B2 = *(const float4*)&bt2[c0+8], B3 = *(const float4*)&bt2[c0+12];
        y[0]=siluf(fmaf((v0.x-mu)*inv,G0.x,B0.x));  y[1]=siluf(fmaf((v0.y-mu)*inv,G0.y,B0.y));
        y[2]=siluf(fmaf((v0.z-mu)*inv,G0.z,B0.z));  y[3]=siluf(fmaf((v0.w-mu)*inv,G0.w,B0.w));
        y[4]=siluf(fmaf((v1.x-mu)*inv,G1v.x,B1.x)); y[5]=siluf(fmaf((v1.y-mu)*inv,G1v.y,B1.y));
        y[6]=siluf(fmaf((v1.z-mu)*inv,G1v.z,B1.z)); y[7]=siluf(fmaf((v1.w-mu)*inv,G1v.w,B1.w));
        y[8]=siluf(fmaf((v2.x-mu)*inv,G2.x,B2.x));  y[9]=siluf(fmaf((v2.y-mu)*inv,G2.y,B2.y));
        y[10]=siluf(fmaf((v2.z-mu)*inv,G2.z,B2.z)); y[11]=siluf(fmaf((v2.w-mu)*inv,G2.w,B2.w));
        y[12]=siluf(fmaf((v3.x-mu)*inv,G3.x,B3.x)); y[13]=siluf(fmaf((v3.y-mu)*inv,G3.y,B3.y));
        y[14]=siluf(fmaf((v3.z-mu)*inv,G3.z,B3.z)); y[15]=siluf(fmaf((v3.w-mu)*inv,G3.w,B3.w));
    }
    __syncthreads();
    {
        U8h ha, hb2;
        #pragma unroll
        for (int j = 0; j < 8; ++j) {
            ha.a[j]  = (f16)y[j];
            hb2.a[j] = (f16)y[8+j];
        }
        const int cA = (2*(tid & 7))     ^ (eLN & 15);
        const int cB = (2*(tid & 7) + 1) ^ (eLN & 15);
        *(f16x8*)&sY[eLN*128 + (cA << 3)] = ha.v;
        *(f16x8*)&sY[eLN*128 + (cB << 3)] = hb2.v;
    }
    __syncthreads();

    f32x4 d00={0,0,0,0}, d01={0,0,0,0}, d10={0,0,0,0}, d11={0,0,0,0};
    {
        const f16* c2F0 = B2T + (size_t)colB0*HID + lh*8;
        const f16* c2F1 = B2T + (size_t)colB1*HID + lh*8;
        f16x8 wf0 = *(const f16x8*)c2F0, wf1 = *(const f16x8*)c2F1;
        #pragma unroll
        for (int s = 0; s < 4; ++s) {
            f16x8 nf0 = wf0, nf1 = wf1;
            if (s < 3) {
                nf0 = *(const f16x8*)(c2F0 + 32*(s+1));
                nf1 = *(const f16x8*)(c2F1 + 32*(s+1));
            }
            const int c4 = s*4 + lh;
            const int i0 = lr*128 + ((c4 ^ lr) << 3);
            const int i1 = (16+lr)*128 + ((c4 ^ lr) << 3);
            f16x8 ah0 = *(const f16x8*)&sY[i0], ah1 = *(const f16x8*)&sY[i1];
            d00 = mfma16(ah0, wf0, d00);
            d01 = mfma16(ah0, wf1, d01);
            d10 = mfma16(ah1, wf0, d10);
            d11 = mfma16(ah1, wf1, d11);
            wf0 = nf0; wf1 = nf1;
        }
    }

    {
        const float b20 = bn2[colB0], b21 = bn2[colB1];
        #pragma unroll
        for (int j = 0; j < 4; ++j) {
            const int r0 = 4*lh + j, r1 = 16 + 4*lh + j;
            const size_t i00 = (size_t)(node0+r0)*HID + colB0;
            const size_t i01 = (size_t)(node0+r0)*HID + colB1;
            const size_t i10 = (size_t)(node0+r1)*HID + colB0;
            const size_t i11 = (size_t)(node0+r1)*HID + colB1;
            float v00 = hh[i00] + d00[j] + b20;
            float v01 = hh[i01] + d01[j] + b21;
            float v10 = hh[i10] + d10[j] + b20;
            float v11 = hh[i11] + d11[j] + b21;
            hh[i00] = v00; hh[i01] = v01; hh[i10] = v10; hh[i11] = v11;
            hhF[i00] = (f16)v00; hhF[i01] = (f16)v01;
            hhF[i10] = (f16)v10; hhF[i11] = (f16)v11;
        }
    }
}

// ---------------------------------------------------------------- output head
__global__ __launch_bounds__(HID) void out_k(
    const float* __restrict__ hh, const float* __restrict__ Woe,
    const float* __restrict__ boe, const float* __restrict__ Wf,
    const float* __restrict__ bf, float* __restrict__ out)
{
    __shared__ float sH[HID];
    const int lig = blockIdx.x, tid = threadIdx.x;
    float s = 0.0f;
    const float* base = hh + (size_t)lig*KAT*HID + tid;
    #pragma unroll 8
    for (int a = 0; a < KAT; ++a) s += base[a*HID];
    sH[tid] = s * (1.0f/KAT);
    __syncthreads();

    float contrib = 0.0f;
    if (tid < OUTF) {
        float p = boe[tid];
        #pragma unroll 4
        for (int i = 0; i < HID; ++i)
            p = fmaf(sH[i], Woe[i*OUTF + tid], p);
        contrib = p * Wf[tid];
    }
    #pragma unroll
    for (int m = 1; m < 64; m <<= 1) contrib += __shfl_xor(contrib, m);
    if (tid == 0) out[lig] = contrib + bf[0];
}

// ---------------------------------------------------------------- launch
extern "C" void kernel_launch(void* const* d_in, const int* in_sizes, int n_in,
                              void* d_out, int out_size, void* d_ws, size_t ws_size,
                              hipStream_t stream)
{
    (void)in_sizes; (void)n_in; (void)out_size; (void)ws_size;
    const float* x    = (const float*)d_in[0];
    const float* h    = (const float*)d_in[1];
    const int*   t    = (const int*)d_in[2];
    const int*   edges= (const int*)d_in[3];
    const int*   tb   = (const int*)d_in[4];
    const float* temb = (const float*)d_in[8];
    const float* Win  = (const float*)d_in[9];
    const float* bin  = (const float*)d_in[10];
    const float* We1  = (const float*)d_in[11];
    const float* be1  = (const float*)d_in[12];
    const float* g1   = (const float*)d_in[13];
    const float* bt1  = (const float*)d_in[14];
    const float* We2  = (const float*)d_in[15];
    const float* be2  = (const float*)d_in[16];
    const float* Watt = (const float*)d_in[17];
    const float* batt = (const float*)d_in[18];
    const float* Wn1  = (const float*)d_in[19];
    const float* bn1  = (const float*)d_in[20];
    const float* g2   = (const float*)d_in[21];
    const float* bt2  = (const float*)d_in[22];
    const float* Wn2  = (const float*)d_in[23];
    const float* bn2  = (const float*)d_in[24];
    const float* Woe  = (const float*)d_in[25];
    const float* boe  = (const float*)d_in[26];
    const float* Wf   = (const float*)d_in[27];
    const float* bf   = (const float*)d_in[28];
    float* out = (float*)d_out;

    char* wsb = (char*)d_ws;
    float* hh  = (float*)(wsb);                        // 16 MB
    f16* hhF   = (f16*)(wsb + ((size_t)16<<20));       // 8 MB
    f16* aggF  = (f16*)(wsb + ((size_t)24<<20));       // 8 MB
    f16* tembF = (f16*)(wsb + ((size_t)32<<20));
    f16* W1T   = tembF + PREP_TEMB;
    f16* W2T   = W1T + PREP_W1;
    f16* WN1T  = W2T + PREP_W2;
    f16* WN2T  = WN1T + PREP_WN1;

    prep_k<<<(PREP_TOT + 255)/256, 256, 0, stream>>>(
        temb, We1, We2, Wn1, Wn2, tembF, W1T, W2T, WN1T, WN2T);

    embed_k<<<NNODES/8, 256, 0, stream>>>(h, t, temb, Win, bin, hh, hhF);

    for (int l = 0; l < 4; ++l) {
        edge_k<<<NNODES/NPB, 512, 0, stream>>>(
            hhF, x, edges + NEDGES, tb, tembF,
            W1T + (size_t)l*128*K1, W2T + (size_t)l*128*128,
            be1 + l*HID, g1 + l*HID, bt1 + l*HID, be2 + l*HID,
            Watt + l*HID, batt + l, aggF);
        node_k<<<NNODES/32, 256, 0, stream>>>(
            hh, hhF, aggF,
            WN1T + (size_t)l*128*256, WN2T + (size_t)l*128*128,
            bn1 + l*HID, g2 + l*HID, bt2 + l*HID, bn2 + l*HID);
    }
    out_k<<<NLIG, HID, 0, stream>>>(hh, Woe, boe, Wf, bf, out);
}

// Round 16
// 480.671 us; speedup vs baseline: 1.2545x; 1.2545x over previous
//
#include <hip/hip_runtime.h>
#include <math.h>

#define NNODES 32768
#define NLIG   1024
#define KAT    32
#define KNN    8
#define NEDGES (NNODES*KNN)
#define HID    128
#define TF     16
#define NG     20
#define OUTF   64

#define NPB    16           // nodes per edge-block
#define EPB    128          // edges per edge-block
#define K1     320          // padded GEMM1 K (292 -> 320)
#define MIDSTR 132          // node_k sMid row stride (floats)

typedef unsigned short u16;
typedef _Float16 f16;
typedef __attribute__((__ext_vector_type__(8))) _Float16 f16x8;
typedef __attribute__((__ext_vector_type__(4))) float f32x4;

union U8h { f16 a[8]; f16x8 v; };

// Gaussian smearing constants: og[g] = 5^(g/19)-1, coeff = -0.5/diff^2
__device__ const float GS_OG[20] = {
    0.0f, 0.0883984f, 0.1845966f, 0.2893285f, 0.4033028f,
    0.5273539f, 0.6623701f, 0.8093209f, 0.9692606f, 1.1433389f,
    1.3328075f, 1.5390240f, 1.7634662f, 2.0077560f, 2.2736369f,
    2.5630207f, 2.8779861f, 3.2207938f, 3.5939058f, 4.0f };
__device__ const float GS_CF[20] = {
    -63.9853f, -63.9853f, -54.0303f, -45.5840f, -38.4908f,
    -32.4913f, -27.4283f, -23.1540f, -19.5460f, -16.4999f,
    -13.9282f, -11.7577f, -9.92569f, -8.37837f, -7.07287f,
    -5.97065f, -5.04016f, -4.25470f, -3.59163f, -3.03191f };

__device__ __forceinline__ float siluf(float v) {
    return __fdividef(v, 1.0f + __expf(-v));
}
__device__ __forceinline__ float sigf(float v) {
    return __fdividef(1.0f, 1.0f + __expf(-v));
}
__device__ __forceinline__ f32x4 mfma16(f16x8 a, f16x8 b, f32x4 c) {
    return __builtin_amdgcn_mfma_f32_16x16x32_f16(a, b, c, 0, 0, 0);
}

// ---------------------------------------------------------------- prep (fp16 single)
#define PREP_TEMB 16000
#define PREP_W1   (4*128*K1)       // 163840
#define PREP_W2   (4*128*128)      // 65536
#define PREP_WN1  (4*128*256)      // 131072
#define PREP_WN2  (4*128*128)      // 65536
#define PREP_TOT  (PREP_TEMB+PREP_W1+PREP_W2+PREP_WN1+PREP_WN2)

__global__ __launch_bounds__(256) void prep_k(
    const float* __restrict__ temb, const float* __restrict__ We1,
    const float* __restrict__ We2,  const float* __restrict__ Wn1,
    const float* __restrict__ Wn2,
    f16* __restrict__ tembF,
    f16* __restrict__ W1T, f16* __restrict__ W2T,
    f16* __restrict__ WN1T, f16* __restrict__ WN2T)
{
    int i = blockIdx.x*256 + threadIdx.x;
    if (i >= PREP_TOT) return;
    float v; f16* dst; int di;
    if (i < PREP_TEMB) {
        v = temb[i]; dst = tembF; di = i;
    } else if (i < PREP_TEMB + PREP_W1) {
        int j = i - PREP_TEMB; di = j; dst = W1T;
        int l = j / (128*K1); int r = j - l*(128*K1);
        int col = r / K1, k = r - col*K1;
        v = (k < 292) ? We1[(size_t)l*292*128 + (size_t)k*128 + col] : 0.0f;
    } else if (i < PREP_TEMB + PREP_W1 + PREP_W2) {
        int j = i - PREP_TEMB - PREP_W1; di = j; dst = W2T;
        int l = j >> 14; int r = j & 16383;
        int col = r >> 7, k = r & 127;
        v = We2[(size_t)l*16384 + (size_t)k*128 + col];
    } else if (i < PREP_TEMB + PREP_W1 + PREP_W2 + PREP_WN1) {
        int j = i - PREP_TEMB - PREP_W1 - PREP_W2; di = j; dst = WN1T;
        int l = j >> 15; int r = j & 32767;
        int col = r >> 8, k = r & 255;
        v = Wn1[(size_t)l*32768 + (size_t)k*128 + col];
    } else {
        int j = i - PREP_TEMB - PREP_W1 - PREP_W2 - PREP_WN1; di = j; dst = WN2T;
        int l = j >> 14; int r = j & 16383;
        int col = r >> 7, k = r & 127;
        v = Wn2[(size_t)l*16384 + (size_t)k*128 + col];
    }
    dst[di] = (f16)v;
}

// ---------------------------------------------------------------- embed (8 nodes/block)
__global__ __launch_bounds__(256) void embed_k(
    const float* __restrict__ h, const int* __restrict__ t,
    const float* __restrict__ temb, const float* __restrict__ Win,
    const float* __restrict__ bin, float* __restrict__ hh,
    f16* __restrict__ hhF)
{
    __shared__ float sIn[8][32];
    const int tid = threadIdx.x;
    {
        const int n = tid >> 5, i = tid & 31;
        const int node = blockIdx.x*8 + n;
        sIn[n][i] = (i < TF) ? h[node*TF + i] : temb[t[node]*TF + (i-TF)];
    }
    __syncthreads();
    const int sub = tid >> 7, col = tid & 127;
    float acc[4];
    const float b = bin[col];
    acc[0]=acc[1]=acc[2]=acc[3]=b;
    #pragma unroll 8
    for (int i = 0; i < 32; ++i) {
        const float wv = Win[i*HID + col];
        acc[0] = fmaf(sIn[sub][i],   wv, acc[0]);
        acc[1] = fmaf(sIn[2+sub][i], wv, acc[1]);
        acc[2] = fmaf(sIn[4+sub][i], wv, acc[2]);
        acc[3] = fmaf(sIn[6+sub][i], wv, acc[3]);
    }
    #pragma unroll
    for (int nn = 0; nn < 4; ++nn) {
        const size_t idx = (size_t)(blockIdx.x*8 + nn*2 + sub)*HID + col;
        hh[idx] = acc[nn];
        hhF[idx] = (f16)acc[nn];
    }
}

// ---------------------------------------------------------------- edge
// M=128 (16 nodes, 128 edges/block), fp16 single-product MFMA throughout.
// (256,3): reg cap ~170 fits the 148-reg working set (84 VGPR + 64 acc);
// (256,4)'s 128 cap spilled (round 12), and the 512-thread repartition
// (round 15) regressed: total VALU work unchanged, barriers costlier.
__global__ __launch_bounds__(256, 3) void edge_k(
    const f16* __restrict__ hhF, const float* __restrict__ x,
    const int* __restrict__ ecol, const int* __restrict__ tbond,
    const f16* __restrict__ tembF,
    const f16* __restrict__ W1T, const f16* __restrict__ W2T,
    const float* __restrict__ be1, const float* __restrict__ g1,
    const float* __restrict__ bt1, const float* __restrict__ be2,
    const float* __restrict__ Watt, const float* __restrict__ batt,
    f16* __restrict__ aggF)
{
    // LDS (38400 B):
    //  [0,8192)       tbl (32 atoms x 128 f16)   | after LN: sB2 (128x128 f16 = 32K) [0,32768)
    //  [8192,24576)   tailB (128 x 64 f16)
    //  [32768,36864)  sStats (128 x 4 waves x float2)   | after GEMM2: sAP (512 f32)
    //  [36864,37888)  sMuInv (128 x f32x2)
    //  [37888,38400)  sAttv (128 f32)
    __shared__ __align__(16) char smem[38400];
    f16*   tbl   = (f16*)(smem);
    f16*   tailB = (f16*)(smem + 8192);
    float* sStats= (float*)(smem + 32768);
    float* sMuInv= (float*)(smem + 36864);
    f16*   sB2   = (f16*)(smem);
    float* sAP   = (float*)(smem + 32768);
    float* sAttv = (float*)(smem + 37888);

    const int tid = threadIdx.x;
    const int node0 = blockIdx.x * NPB;
    const int ligBase = node0 & ~31;
    const int aBase   = node0 & 31;      // 0 or 16
    const int w = tid >> 6, lane = tid & 63, lr = lane & 15, lh = lane >> 4;
    const int colB0 = w*32 + lr, colB1 = colB0 + 16;

    // ---- per-lane col atom ids, packed 8x8b into 2 u32 -----------------
    unsigned aColPk0 = 0, aColPk1 = 0;
    #pragma unroll
    for (int rt = 0; rt < 4; ++rt)
        aColPk0 |= (unsigned)(ecol[node0*KNN + rt*16 + lr] & 31) << (rt*8);
    #pragma unroll
    for (int rt = 0; rt < 4; ++rt)
        aColPk1 |= (unsigned)(ecol[node0*KNN + (4+rt)*16 + lr] & 31) << (rt*8);

    // ---- GEMM1 weight pointers + first fragments -----------------------
    const f16* bF0 = W1T + (size_t)colB0*K1 + lh*8;
    const f16* bF1 = W1T + (size_t)colB1*K1 + lh*8;
    f16x8 wf0 = *(const f16x8*)bF0, wf1 = *(const f16x8*)bF1;

    // ---- stage ligand hh table (32 atoms x 16 chunks) ------------------
    for (int idx = tid; idx < 512; idx += 256) {
        const int a = idx >> 4, c4 = idx & 15;
        const f16x8 v = *(const f16x8*)(hhF + (size_t)(ligBase + a)*HID + c4*8);
        *(f16x8*)&tbl[a*128 + ((c4 ^ (a & 15)) << 3)] = v;
    }

    // ---- tail (fp16) [128 rows][8 chunks]: temb(2)|smear(3)|0(3) -------
    for (int pe = tid; pe < 1024; pe += 256) {
        const int row = pe & 127, part = pe >> 7;
        U8h vh;
        if (part < 2) {
            const int r = node0 + (row >> 3);
            const int c = ecol[node0*KNN + row];
            int sbi = r*(KAT-1) + c - (r/KAT)*KAT - (r < c ? 1 : 0);
            const int tb = tbond[sbi];
            #pragma unroll
            for (int j = 0; j < 8; ++j)
                vh.a[j] = tembF[tb*TF + part*8 + j];
        } else if (part < 5) {
            const int r = node0 + (row >> 3);
            const int c = ecol[node0*KNN + row];
            float dx = x[3*r]-x[3*c], dy = x[3*r+1]-x[3*c+1], dz = x[3*r+2]-x[3*c+2];
            float dist = fminf(sqrtf(dx*dx+dy*dy+dz*dz), 4.0f);
            #pragma unroll
            for (int j = 0; j < 8; ++j) {
                int g = (part-2)*8 + j;
                float v = 0.0f;
                if (g < NG) {
                    float dd = dist - GS_OG[g];
                    v = __expf(GS_CF[g]*dd*dd);
                }
                vh.a[j] = (f16)v;
            }
        } else {
            #pragma unroll
            for (int j = 0; j < 8; ++j) vh.a[j] = (f16)0.0f;
        }
        *(f16x8*)&tailB[row*64 + ((part ^ (row & 7)) << 3)] = vh.v;
    }
    __syncthreads();                                    // bar1

    // ---- GEMM1: [128 x 320] @ [320 x 128], 1-deep W prefetch -----------
    f32x4 acc[8][2];
    #pragma unroll
    for (int rt = 0; rt < 8; ++rt) { acc[rt][0] = (f32x4){0,0,0,0}; acc[rt][1] = (f32x4){0,0,0,0}; }
    {
        #pragma unroll
        for (int s = 0; s < 10; ++s) {
            f16x8 nf0 = wf0, nf1 = wf1;
            if (s < 9) {
                nf0 = *(const f16x8*)(bF0 + 32*(s+1));
                nf1 = *(const f16x8*)(bF1 + 32*(s+1));
            }
            if (s < 4) {
                #pragma unroll
                for (int rt = 0; rt < 8; ++rt) {
                    const int aR = aBase + 2*rt + (lr >> 3);
                    const int c4 = s*4 + lh;
                    const int ad = aR*128 + ((c4 ^ (aR & 15)) << 3);
                    const f16x8 ah = *(const f16x8*)&tbl[ad];
                    acc[rt][0] = mfma16(ah, wf0, acc[rt][0]);
                    acc[rt][1] = mfma16(ah, wf1, acc[rt][1]);
                }
            } else if (s < 8) {
                #pragma unroll
                for (int rt = 0; rt < 8; ++rt) {
                    const int aC = (int)((rt < 4 ? (aColPk0 >> (rt*8))
                                                 : (aColPk1 >> ((rt-4)*8))) & 31u);
                    const int c4 = (s-4)*4 + lh;
                    const int ad = aC*128 + ((c4 ^ (aC & 15)) << 3);
                    const f16x8 ah = *(const f16x8*)&tbl[ad];
                    acc[rt][0] = mfma16(ah, wf0, acc[rt][0]);
                    acc[rt][1] = mfma16(ah, wf1, acc[rt][1]);
                }
            } else {
                #pragma unroll
                for (int rt = 0; rt < 8; ++rt) {
                    const int r = rt*16 + lr;
                    const int c = (s-8)*4 + lh;
                    const int ad = r*64 + ((c ^ (r & 7)) << 3);
                    const f16x8 ah = *(const f16x8*)&tailB[ad];
                    acc[rt][0] = mfma16(ah, wf0, acc[rt][0]);
                    acc[rt][1] = mfma16(ah, wf1, acc[rt][1]);
                }
            }
            wf0 = nf0; wf1 = nf1;
        }
    }

    // ---- bias + in-register LN partials --------------------------------
    {
        const float b10 = be1[colB0], b11 = be1[colB1];
        #pragma unroll
        for (int rt = 0; rt < 8; ++rt)
            #pragma unroll
            for (int j = 0; j < 4; ++j) { acc[rt][0][j] += b10; acc[rt][1][j] += b11; }
    }
    {
        #pragma unroll
        for (int rt = 0; rt < 8; ++rt) {
            float sv[4], qv[4];
            #pragma unroll
            for (int j = 0; j < 4; ++j) {
                const float a0 = acc[rt][0][j], a1 = acc[rt][1][j];
                sv[j] = a0 + a1; qv[j] = a0*a0 + a1*a1;
            }
            #pragma unroll
            for (int msk = 1; msk < 16; msk <<= 1) {
                #pragma unroll
                for (int j = 0; j < 4; ++j) {
                    sv[j] += __shfl_xor(sv[j], msk);
                    qv[j] += __shfl_xor(qv[j], msk);
                }
            }
            if (lr == 0) {
                #pragma unroll
                for (int j = 0; j < 4; ++j) {
                    const int row = rt*16 + 4*lh + j;
                    sStats[(row*4 + w)*2 + 0] = sv[j];
                    sStats[(row*4 + w)*2 + 1] = qv[j];
                }
            }
        }
    }
    __syncthreads();                                    // bar2

    if (tid < EPB) {
        const float4 a = *(const float4*)&sStats[tid*8];
        const float4 b = *(const float4*)&sStats[tid*8 + 4];
        const float st = a.x + a.z + b.x + b.z;
        const float qt = a.y + a.w + b.y + b.w;
        const float mu  = st * (1.0f/HID);
        const float var = qt * (1.0f/HID) - mu*mu;
        sMuInv[tid*2 + 0] = mu;
        sMuInv[tid*2 + 1] = rsqrtf(var + 1e-5f);
    }
    __syncthreads();                                    // bar3

    // ---- GEMM2 weight pointers + first fragments -----------------------
    const f16* c2F0 = W2T + (size_t)colB0*HID + lh*8;
    const f16* c2F1 = W2T + (size_t)colB1*HID + lh*8;
    f16x8 g2f0 = *(const f16x8*)c2F0, g2f1 = *(const f16x8*)c2F1;

    // ---- normalize + SiLU in regs, write fp16 acts to sB2 --------------
    {
        const float G0 = g1[colB0], G1s = g1[colB1];
        const float B0 = bt1[colB0], B1s = bt1[colB1];
        #pragma unroll
        for (int rt = 0; rt < 8; ++rt) {
            const int r0 = rt*16 + 4*lh;
            const float4 mi0 = *(const float4*)&sMuInv[r0*2];      // mu0,inv0,mu1,inv1
            const float4 mi1 = *(const float4*)&sMuInv[r0*2 + 4];  // mu2,inv2,mu3,inv3
            acc[rt][0][0] = siluf(fmaf((acc[rt][0][0]-mi0.x)*mi0.y, G0, B0));
            acc[rt][1][0] = siluf(fmaf((acc[rt][1][0]-mi0.x)*mi0.y, G1s, B1s));
            acc[rt][0][1] = siluf(fmaf((acc[rt][0][1]-mi0.z)*mi0.w, G0, B0));
            acc[rt][1][1] = siluf(fmaf((acc[rt][1][1]-mi0.z)*mi0.w, G1s, B1s));
            acc[rt][0][2] = siluf(fmaf((acc[rt][0][2]-mi1.x)*mi1.y, G0, B0));
            acc[rt][1][2] = siluf(fmaf((acc[rt][1][2]-mi1.x)*mi1.y, G1s, B1s));
            acc[rt][0][3] = siluf(fmaf((acc[rt][0][3]-mi1.z)*mi1.w, G0, B0));
            acc[rt][1][3] = siluf(fmaf((acc[rt][1][3]-mi1.z)*mi1.w, G1s, B1s));
        }
    }
    {
        #pragma unroll
        for (int rt = 0; rt < 8; ++rt) {
            #pragma unroll
            for (int hcol = 0; hcol < 2; ++hcol) {
                const int col = hcol ? colB1 : colB0;
                const int gch = col >> 3, cw = col & 7;
                #pragma unroll
                for (int j = 0; j < 4; ++j) {
                    const int row = rt*16 + 4*lh + j;
                    sB2[row*128 + ((gch ^ (row & 15)) << 3) + cw] =
                        (f16)acc[rt][hcol][j];
                }
            }
        }
    }
    __syncthreads();                                    // bar4

    // ---- GEMM2: [128 x 128] @ [128 x 128] ------------------------------
    f32x4 d[8][2];
    #pragma unroll
    for (int rt = 0; rt < 8; ++rt) { d[rt][0] = (f32x4){0,0,0,0}; d[rt][1] = (f32x4){0,0,0,0}; }
    {
        #pragma unroll
        for (int s = 0; s < 4; ++s) {
            f16x8 nf0 = g2f0, nf1 = g2f1;
            if (s < 3) {
                nf0 = *(const f16x8*)(c2F0 + 32*(s+1));
                nf1 = *(const f16x8*)(c2F1 + 32*(s+1));
            }
            #pragma unroll
            for (int rt = 0; rt < 8; ++rt) {
                const int rowL = rt*16 + lr;
                const int c4 = s*4 + lh;
                const f16x8 ah = *(const f16x8*)&sB2[rowL*128 + ((c4 ^ (rowL & 15)) << 3)];
                d[rt][0] = mfma16(ah, g2f0, d[rt][0]);
                d[rt][1] = mfma16(ah, g2f1, d[rt][1]);
            }
            g2f0 = nf0; g2f1 = nf1;
        }
    }

    // ---- SiLU in place (d becomes m) + attention gate ------------------
    {
        const float b20 = be2[colB0], b21 = be2[colB1];
        #pragma unroll
        for (int rt = 0; rt < 8; ++rt) {
            #pragma unroll
            for (int j = 0; j < 4; ++j) {
                d[rt][0][j] = siluf(d[rt][0][j] + b20);
                d[rt][1][j] = siluf(d[rt][1][j] + b21);
            }
        }
    }
    {
        const float wa0 = Watt[colB0], wa1 = Watt[colB1];
        float pa[8][4];
        #pragma unroll
        for (int rt = 0; rt < 8; ++rt)
            #pragma unroll
            for (int j = 0; j < 4; ++j)
                pa[rt][j] = d[rt][0][j]*wa0 + d[rt][1][j]*wa1;
        #pragma unroll
        for (int msk = 1; msk < 16; msk <<= 1) {
            #pragma unroll
            for (int rt = 0; rt < 8; ++rt)
                #pragma unroll
                for (int j = 0; j < 4; ++j)
                    pa[rt][j] += __shfl_xor(pa[rt][j], msk);
        }
        if (lr == 0) {
            #pragma unroll
            for (int rt = 0; rt < 8; ++rt)
                #pragma unroll
                for (int j = 0; j < 4; ++j)
                    sAP[w*128 + rt*16 + 4*lh + j] = pa[rt][j];
        }
    }
    __syncthreads();                                    // bar5
    if (tid < EPB)
        sAttv[tid] = sigf(sAP[tid] + sAP[128+tid] + sAP[256+tid] + sAP[384+tid] + batt[0]);
    __syncthreads();                                    // bar6

    // ---- gated aggregate -> aggF ---------------------------------------
    #pragma unroll
    for (int rt = 0; rt < 8; ++rt) {
        float s0 = 0.0f, s1 = 0.0f;
        #pragma unroll
        for (int j = 0; j < 4; ++j) {
            const float av = sAttv[rt*16 + 4*lh + j];
            s0 += d[rt][0][j]*av;
            s1 += d[rt][1][j]*av;
        }
        s0 += __shfl_xor(s0, 16);
        s1 += __shfl_xor(s1, 16);
        if ((lh & 1) == 0) {
            const int node = node0 + 2*rt + (lh >> 1);
            aggF[(size_t)node*HID + colB0] = (f16)(s0*0.2f);
            aggF[(size_t)node*HID + colB1] = (f16)(s1*0.2f);
        }
    }
}

// ---------------------------------------------------------------- node (fp16 MFMA, 32 nodes/block)
__global__ __launch_bounds__(256, 6) void node_k(
    float* __restrict__ hh, f16* __restrict__ hhF,
    const f16* __restrict__ aggF,
    const f16* __restrict__ B1T, const f16* __restrict__ B2T,
    const float* __restrict__ bn1, const float* __restrict__ g2,
    const float* __restrict__ bt2, const float* __restrict__ bn2)
{
    __shared__ __align__(16) char smem[16896];
    float* sMid = (float*)smem;
    f16* sY = (f16*)smem;                // fp16 post-LN acts (8 KB)

    const int tid = threadIdx.x;
    const int node0 = blockIdx.x * 32;
    const int w = tid >> 6, lane = tid & 63, lr = lane & 15, lh = lane >> 4;
    const int colB0 = w*32 + lr, colB1 = colB0 + 16;

    const f16* a1f = hhF  + (size_t)(node0+lr)*HID + lh*8;
    const f16* a2f = aggF + (size_t)(node0+lr)*HID + lh*8;
    const f16* c1F0 = B1T + (size_t)colB0*256 + lh*8;
    const f16* c1F1 = B1T + (size_t)colB1*256 + lh*8;

    f32x4 acc00={0,0,0,0}, acc01={0,0,0,0}, acc10={0,0,0,0}, acc11={0,0,0,0};
    {
        f16x8 wf0 = *(const f16x8*)c1F0, wf1 = *(const f16x8*)c1F1;
        #pragma unroll
        for (int s = 0; s < 8; ++s) {
            f16x8 nf0 = wf0, nf1 = wf1;
            if (s < 7) {
                nf0 = *(const f16x8*)(c1F0 + 32*(s+1));
                nf1 = *(const f16x8*)(c1F1 + 32*(s+1));
            }
            f16x8 ah0, ah1;
            if (s < 4) {
                ah0 = *(const f16x8*)(a1f + 32*s);
                ah1 = *(const f16x8*)(a1f + 16*HID + 32*s);
            } else {
                ah0 = *(const f16x8*)(a2f + 32*(s-4));
                ah1 = *(const f16x8*)(a2f + 16*HID + 32*(s-4));
            }
            acc00 = mfma16(ah0, wf0, acc00);
            acc01 = mfma16(ah0, wf1, acc01);
            acc10 = mfma16(ah1, wf0, acc10);
            acc11 = mfma16(ah1, wf1, acc11);
            wf0 = nf0; wf1 = nf1;
        }
    }
    {
        const float b10 = bn1[colB0], b11 = bn1[colB1];
        #pragma unroll
        for (int j = 0; j < 4; ++j) {
            const int r0 = 4*lh + j;
            sMid[r0*MIDSTR + colB0]      = acc00[j] + b10;
            sMid[r0*MIDSTR + colB1]      = acc01[j] + b11;
            sMid[(16+r0)*MIDSTR + colB0] = acc10[j] + b10;
            sMid[(16+r0)*MIDSTR + colB1] = acc11[j] + b11;
        }
    }
    __syncthreads();

    float y[16];
    const int eLN = tid >> 3, c0 = (tid & 7)*16;
    {
        const float* mrow = &sMid[eLN*MIDSTR + c0];
        float4 v0 = *(const float4*)&mrow[0];
        float4 v1 = *(const float4*)&mrow[4];
        float4 v2 = *(const float4*)&mrow[8];
        float4 v3 = *(const float4*)&mrow[12];
        float s = v0.x+v0.y+v0.z+v0.w + v1.x+v1.y+v1.z+v1.w
                + v2.x+v2.y+v2.z+v2.w + v3.x+v3.y+v3.z+v3.w;
        float q = v0.x*v0.x+v0.y*v0.y+v0.z*v0.z+v0.w*v0.w
                + v1.x*v1.x+v1.y*v1.y+v1.z*v1.z+v1.w*v1.w
                + v2.x*v2.x+v2.y*v2.y+v2.z*v2.z+v2.w*v2.w
                + v3.x*v3.x+v3.y*v3.y+v3.z*v3.z+v3.w*v3.w;
        #pragma unroll
        for (int m = 4; m >= 1; m >>= 1) { s += __shfl_xor(s, m); q += __shfl_xor(q, m); }
        float mu  = s * (1.0f/HID);
        float var = q * (1.0f/HID) - mu*mu;
        float inv = rsqrtf(var + 1e-5f);
        const float4 G0 = *(const float4*)&g2[c0+0],  G1v = *(const float4*)&g2[c0+4];
        const float4 G2 = *(const float4*)&g2[c0+8],  G3 = *(const float4*)&g2[c0+12];
        const float4 B0 = *(const float4*)&bt2[c0+0], B1 = *(const float4*)&bt2[c0+4];
        const float4 B2 = *(const float4*)&bt2[c0+8], B3 = *(const float4*)&bt2[c0+12];
        y[0]=siluf(fmaf((v0.x-mu)*inv,G0.x,B0.x));  y[1]=siluf(fmaf((v0.y-mu)*inv,G0.y,B0.y));
        y[2]=siluf(fmaf((v0.z-mu)*inv,G0.z,B0.z));  y[3]=siluf(fmaf((v0.w-mu)*inv,G0.w,B0.w));
        y[4]=siluf(fmaf((v1.x-mu)*inv,G1v.x,B1.x)); y[5]=siluf(fmaf((v1.y-mu)*inv,G1v.y,B1.y));
        y[6]=siluf(fmaf((v1.z-mu)*inv,G1v.z,B1.z)); y[7]=siluf(fmaf((v1.w-mu)*inv,G1v.w,B1.w));
        y[8]=siluf(fmaf((v2.x-mu)*inv,G2.x,B2.x));  y[9]=siluf(fmaf((v2.y-mu)*inv,G2.y,B2.y));
        y[10]=siluf(fmaf((v2.z-mu)*inv,G2.z,B2.z)); y[11]=siluf(fmaf((v2.w-mu)*inv,G2.w,B2.w));
        y[12]=siluf(fmaf((v3.x-mu)*inv,G3.x,B3.x)); y[13]=siluf(fmaf((v3.y-mu)*inv,G3.y,B3.y));
        y[14]=siluf(fmaf((v3.z-mu)*inv,G3.z,B3.z)); y[15]=siluf(fmaf((v3.w-mu)*inv,G3.w,B3.w));
    }
    __syncthreads();
    {
        U8h ha, hb2;
        #pragma unroll
        for (int j = 0; j < 8; ++j) {
            ha.a[j]  = (f16)y[j];
            hb2.a[j] = (f16)y[8+j];
        }
        const int cA = (2*(tid & 7))     ^ (eLN & 15);
        const int cB = (2*(tid & 7) + 1) ^ (eLN & 15);
        *(f16x8*)&sY[eLN*128 + (cA << 3)] = ha.v;
        *(f16x8*)&sY[eLN*128 + (cB << 3)] = hb2.v;
    }
    __syncthreads();

    f32x4 d00={0,0,0,0}, d01={0,0,0,0}, d10={0,0,0,0}, d11={0,0,0,0};
    {
        const f16* c2F0 = B2T + (size_t)colB0*HID + lh*8;
        const f16* c2F1 = B2T + (size_t)colB1*HID + lh*8;
        f16x8 wf0 = *(const f16x8*)c2F0, wf1 = *(const f16x8*)c2F1;
        #pragma unroll
        for (int s = 0; s < 4; ++s) {
            f16x8 nf0 = wf0, nf1 = wf1;
            if (s < 3) {
                nf0 = *(const f16x8*)(c2F0 + 32*(s+1));
                nf1 = *(const f16x8*)(c2F1 + 32*(s+1));
            }
            const int c4 = s*4 + lh;
            const int i0 = lr*128 + ((c4 ^ lr) << 3);
            const int i1 = (16+lr)*128 + ((c4 ^ lr) << 3);
            f16x8 ah0 = *(const f16x8*)&sY[i0], ah1 = *(const f16x8*)&sY[i1];
            d00 = mfma16(ah0, wf0, d00);
            d01 = mfma16(ah0, wf1, d01);
            d10 = mfma16(ah1, wf0, d10);
            d11 = mfma16(ah1, wf1, d11);
            wf0 = nf0; wf1 = nf1;
        }
    }

    {
        const float b20 = bn2[colB0], b21 = bn2[colB1];
        #pragma unroll
        for (int j = 0; j < 4; ++j) {
            const int r0 = 4*lh + j, r1 = 16 + 4*lh + j;
            const size_t i00 = (size_t)(node0+r0)*HID + colB0;
            const size_t i01 = (size_t)(node0+r0)*HID + colB1;
            const size_t i10 = (size_t)(node0+r1)*HID + colB0;
            const size_t i11 = (size_t)(node0+r1)*HID + colB1;
            float v00 = hh[i00] + d00[j] + b20;
            float v01 = hh[i01] + d01[j] + b21;
            float v10 = hh[i10] + d10[j] + b20;
            float v11 = hh[i11] + d11[j] + b21;
            hh[i00] = v00; hh[i01] = v01; hh[i10] = v10; hh[i11] = v11;
            hhF[i00] = (f16)v00; hhF[i01] = (f16)v01;
            hhF[i10] = (f16)v10; hhF[i11] = (f16)v11;
        }
    }
}

// ---------------------------------------------------------------- output head
__global__ __launch_bounds__(HID) void out_k(
    const float* __restrict__ hh, const float* __restrict__ Woe,
    const float* __restrict__ boe, const float* __restrict__ Wf,
    const float* __restrict__ bf, float* __restrict__ out)
{
    __shared__ float sH[HID];
    const int lig = blockIdx.x, tid = threadIdx.x;
    float s = 0.0f;
    const float* base = hh + (size_t)lig*KAT*HID + tid;
    #pragma unroll 8
    for (int a = 0; a < KAT; ++a) s += base[a*HID];
    sH[tid] = s * (1.0f/KAT);
    __syncthreads();

    float contrib = 0.0f;
    if (tid < OUTF) {
        float p = boe[tid];
        #pragma unroll 4
        for (int i = 0; i < HID; ++i)
            p = fmaf(sH[i], Woe[i*OUTF + tid], p);
        contrib = p * Wf[tid];
    }
    #pragma unroll
    for (int m = 1; m < 64; m <<= 1) contrib += __shfl_xor(contrib, m);
    if (tid == 0) out[lig] = contrib + bf[0];
}

// ---------------------------------------------------------------- launch
extern "C" void kernel_launch(void* const* d_in, const int* in_sizes, int n_in,
                              void* d_out, int out_size, void* d_ws, size_t ws_size,
                              hipStream_t stream)
{
    (void)in_sizes; (void)n_in; (void)out_size; (void)ws_size;
    const float* x    = (const float*)d_in[0];
    const float* h    = (const float*)d_in[1];
    const int*   t    = (const int*)d_in[2];
    const int*   edges= (const int*)d_in[3];
    const int*   tb   = (const int*)d_in[4];
    const float* temb = (const float*)d_in[8];
    const float* Win  = (const float*)d_in[9];
    const float* bin  = (const float*)d_in[10];
    const float* We1  = (const float*)d_in[11];
    const float* be1  = (const float*)d_in[12];
    const float* g1   = (const float*)d_in[13];
    const float* bt1  = (const float*)d_in[14];
    const float* We2  = (const float*)d_in[15];
    const float* be2  = (const float*)d_in[16];
    const float* Watt = (const float*)d_in[17];
    const float* batt = (const float*)d_in[18];
    const float* Wn1  = (const float*)d_in[19];
    const float* bn1  = (const float*)d_in[20];
    const float* g2   = (const float*)d_in[21];
    const float* bt2  = (const float*)d_in[22];
    const float* Wn2  = (const float*)d_in[23];
    const float* bn2  = (const float*)d_in[24];
    const float* Woe  = (const float*)d_in[25];
    const float* boe  = (const float*)d_in[26];
    const float* Wf   = (const float*)d_in[27];
    const float* bf   = (const float*)d_in[28];
    float* out = (float*)d_out;

    char* wsb = (char*)d_ws;
    float* hh  = (float*)(wsb);                        // 16 MB
    f16* hhF   = (f16*)(wsb + ((size_t)16<<20));       // 8 MB
    f16* aggF  = (f16*)(wsb + ((size_t)24<<20));       // 8 MB
    f16* tembF = (f16*)(wsb + ((size_t)32<<20));
    f16* W1T   = tembF + PREP_TEMB;
    f16* W2T   = W1T + PREP_W1;
    f16* WN1T  = W2T + PREP_W2;
    f16* WN2T  = WN1T + PREP_WN1;

    prep_k<<<(PREP_TOT + 255)/256, 256, 0, stream>>>(
        temb, We1, We2, Wn1, Wn2, tembF, W1T, W2T, WN1T, WN2T);

    embed_k<<<NNODES/8, 256, 0, stream>>>(h, t, temb, Win, bin, hh, hhF);

    for (int l = 0; l < 4; ++l) {
        edge_k<<<NNODES/NPB, 256, 0, stream>>>(
            hhF, x, edges + NEDGES, tb, tembF,
            W1T + (size_t)l*128*K1, W2T + (size_t)l*128*128,
            be1 + l*HID, g1 + l*HID, bt1 + l*HID, be2 + l*HID,
            Watt + l*HID, batt + l, aggF);
        node_k<<<NNODES/32, 256, 0, stream>>>(
            hh, hhF, aggF,
            WN1T + (size_t)l*128*256, WN2T + (size_t)l*128*128,
            bn1 + l*HID, g2 + l*HID, bt2 + l*HID, bn2 + l*HID);
    }
    out_k<<<NLIG, HID, 0, stream>>>(hh, Woe, boe, Wf, bf, out);
}

// Round 17
// 456.525 us; speedup vs baseline: 1.3209x; 1.0529x over previous
//
#include <hip/hip_runtime.h>
#include <math.h>

#define NNODES 32768
#define NLIG   1024
#define KAT    32
#define KNN    8
#define NEDGES (NNODES*KNN)
#define HID    128
#define TF     16
#define NG     20
#define OUTF   64

#define NPB    16           // nodes per edge-block
#define EPB    128          // edges per edge-block
#define K1     320          // padded GEMM1 K (292 -> 320)

typedef unsigned short u16;
typedef _Float16 f16;
typedef __attribute__((__ext_vector_type__(8))) _Float16 f16x8;
typedef __attribute__((__ext_vector_type__(4))) float f32x4;

union U8h { f16 a[8]; f16x8 v; };

// Gaussian smearing constants: og[g] = 5^(g/19)-1, coeff = -0.5/diff^2
__device__ const float GS_OG[20] = {
    0.0f, 0.0883984f, 0.1845966f, 0.2893285f, 0.4033028f,
    0.5273539f, 0.6623701f, 0.8093209f, 0.9692606f, 1.1433389f,
    1.3328075f, 1.5390240f, 1.7634662f, 2.0077560f, 2.2736369f,
    2.5630207f, 2.8779861f, 3.2207938f, 3.5939058f, 4.0f };
__device__ const float GS_CF[20] = {
    -63.9853f, -63.9853f, -54.0303f, -45.5840f, -38.4908f,
    -32.4913f, -27.4283f, -23.1540f, -19.5460f, -16.4999f,
    -13.9282f, -11.7577f, -9.92569f, -8.37837f, -7.07287f,
    -5.97065f, -5.04016f, -4.25470f, -3.59163f, -3.03191f };

__device__ __forceinline__ float siluf(float v) {
    return __fdividef(v, 1.0f + __expf(-v));
}
__device__ __forceinline__ float sigf(float v) {
    return __fdividef(1.0f, 1.0f + __expf(-v));
}
__device__ __forceinline__ f32x4 mfma16(f16x8 a, f16x8 b, f32x4 c) {
    return __builtin_amdgcn_mfma_f32_16x16x32_f16(a, b, c, 0, 0, 0);
}

// ---------------------------------------------------------------- prep (fp16 single)
#define PREP_TEMB 16000
#define PREP_W1   (4*128*K1)       // 163840
#define PREP_W2   (4*128*128)      // 65536
#define PREP_WN1  (4*128*256)      // 131072
#define PREP_WN2  (4*128*128)      // 65536
#define PREP_TOT  (PREP_TEMB+PREP_W1+PREP_W2+PREP_WN1+PREP_WN2)

__global__ __launch_bounds__(256) void prep_k(
    const float* __restrict__ temb, const float* __restrict__ We1,
    const float* __restrict__ We2,  const float* __restrict__ Wn1,
    const float* __restrict__ Wn2,
    f16* __restrict__ tembF,
    f16* __restrict__ W1T, f16* __restrict__ W2T,
    f16* __restrict__ WN1T, f16* __restrict__ WN2T)
{
    int i = blockIdx.x*256 + threadIdx.x;
    if (i >= PREP_TOT) return;
    float v; f16* dst; int di;
    if (i < PREP_TEMB) {
        v = temb[i]; dst = tembF; di = i;
    } else if (i < PREP_TEMB + PREP_W1) {
        int j = i - PREP_TEMB; di = j; dst = W1T;
        int l = j / (128*K1); int r = j - l*(128*K1);
        int col = r / K1, k = r - col*K1;
        v = (k < 292) ? We1[(size_t)l*292*128 + (size_t)k*128 + col] : 0.0f;
    } else if (i < PREP_TEMB + PREP_W1 + PREP_W2) {
        int j = i - PREP_TEMB - PREP_W1; di = j; dst = W2T;
        int l = j >> 14; int r = j & 16383;
        int col = r >> 7, k = r & 127;
        v = We2[(size_t)l*16384 + (size_t)k*128 + col];
    } else if (i < PREP_TEMB + PREP_W1 + PREP_W2 + PREP_WN1) {
        int j = i - PREP_TEMB - PREP_W1 - PREP_W2; di = j; dst = WN1T;
        int l = j >> 15; int r = j & 32767;
        int col = r >> 8, k = r & 255;
        v = Wn1[(size_t)l*32768 + (size_t)k*128 + col];
    } else {
        int j = i - PREP_TEMB - PREP_W1 - PREP_W2 - PREP_WN1; di = j; dst = WN2T;
        int l = j >> 14; int r = j & 16383;
        int col = r >> 7, k = r & 127;
        v = Wn2[(size_t)l*16384 + (size_t)k*128 + col];
    }
    dst[di] = (f16)v;
}

// ---------------------------------------------------------------- embed (8 nodes/block)
__global__ __launch_bounds__(256) void embed_k(
    const float* __restrict__ h, const int* __restrict__ t,
    const float* __restrict__ temb, const float* __restrict__ Win,
    const float* __restrict__ bin, float* __restrict__ hh,
    f16* __restrict__ hhF)
{
    __shared__ float sIn[8][32];
    const int tid = threadIdx.x;
    {
        const int n = tid >> 5, i = tid & 31;
        const int node = blockIdx.x*8 + n;
        sIn[n][i] = (i < TF) ? h[node*TF + i] : temb[t[node]*TF + (i-TF)];
    }
    __syncthreads();
    const int sub = tid >> 7, col = tid & 127;
    float acc[4];
    const float b = bin[col];
    acc[0]=acc[1]=acc[2]=acc[3]=b;
    #pragma unroll 8
    for (int i = 0; i < 32; ++i) {
        const float wv = Win[i*HID + col];
        acc[0] = fmaf(sIn[sub][i],   wv, acc[0]);
        acc[1] = fmaf(sIn[2+sub][i], wv, acc[1]);
        acc[2] = fmaf(sIn[4+sub][i], wv, acc[2]);
        acc[3] = fmaf(sIn[6+sub][i], wv, acc[3]);
    }
    #pragma unroll
    for (int nn = 0; nn < 4; ++nn) {
        const size_t idx = (size_t)(blockIdx.x*8 + nn*2 + sub)*HID + col;
        hh[idx] = acc[nn];
        hhF[idx] = (f16)acc[nn];
    }
}

// ---------------------------------------------------------------- fused edge+node
// M=128 edges (16 nodes) per block. Edge MLP -> agg stays in LDS -> node MLP
// fused (agg[n] & hh[n] are block-local: all 8 edges of n are in this block).
// LDS 46.6 KB (tbl NOT aliased by sB2 -- node GEMM needs it), 3 blocks/CU.
__global__ __launch_bounds__(256, 3) void fused_k(
    float* __restrict__ hh, f16* __restrict__ hhF,
    const float* __restrict__ x,
    const int* __restrict__ ecol, const int* __restrict__ tbond,
    const f16* __restrict__ tembF,
    const f16* __restrict__ W1T, const f16* __restrict__ W2T,
    const f16* __restrict__ WN1T, const f16* __restrict__ WN2T,
    const float* __restrict__ be1, const float* __restrict__ g1,
    const float* __restrict__ bt1, const float* __restrict__ be2,
    const float* __restrict__ Watt, const float* __restrict__ batt,
    const float* __restrict__ bn1, const float* __restrict__ gn,
    const float* __restrict__ btn, const float* __restrict__ bn2)
{
    // LDS (46592 B):
    //  [0,8192)       tbl (32 atoms x 128 f16)  -- LIVE until node GEMM_n1
    //  [8192,40960)   sB2 (128x128 f16, 32 KB); tailB (16 KB) aliases its
    //                 low half before bar2; sAgg[16][128] f16 at +8192 and
    //                 sY[16][128] f16 at +12288 alias it after GEMM2 reads.
    //  [40960,45056)  sStats (128 x 4 waves x f32x2); sAP (512 f32) aliases
    //  [45056,46080)  sMuInv (128 x f32x2)
    //  [46080,46592)  sAttv (128 f32)
    __shared__ __align__(16) char smem[46592];
    f16*   tbl   = (f16*)(smem);
    f16*   sB2   = (f16*)(smem + 8192);
    f16*   tailB = (f16*)(smem + 8192);
    f16*   sAgg  = (f16*)(smem + 8192);
    f16*   sY    = (f16*)(smem + 12288);
    float* sStats= (float*)(smem + 40960);
    float* sAP   = (float*)(smem + 40960);
    float* sMuInv= (float*)(smem + 45056);
    float* sAttv = (float*)(smem + 46080);

    const int tid = threadIdx.x;
    const int node0 = blockIdx.x * NPB;
    const int ligBase = node0 & ~31;
    const int aBase   = node0 & 31;      // 0 or 16
    const int w = tid >> 6, lane = tid & 63, lr = lane & 15, lh = lane >> 4;
    const int colB0 = w*32 + lr, colB1 = colB0 + 16;

    // ---- per-lane col atom ids, packed 8x8b into 2 u32 -----------------
    unsigned aColPk0 = 0, aColPk1 = 0;
    #pragma unroll
    for (int rt = 0; rt < 4; ++rt)
        aColPk0 |= (unsigned)(ecol[node0*KNN + rt*16 + lr] & 31) << (rt*8);
    #pragma unroll
    for (int rt = 0; rt < 4; ++rt)
        aColPk1 |= (unsigned)(ecol[node0*KNN + (4+rt)*16 + lr] & 31) << (rt*8);

    // ---- GEMM1 weight pointers + first fragments -----------------------
    const f16* bF0 = W1T + (size_t)colB0*K1 + lh*8;
    const f16* bF1 = W1T + (size_t)colB1*K1 + lh*8;
    f16x8 wf0 = *(const f16x8*)bF0, wf1 = *(const f16x8*)bF1;

    // ---- stage ligand hh table (32 atoms x 16 chunks) ------------------
    for (int idx = tid; idx < 512; idx += 256) {
        const int a = idx >> 4, c4 = idx & 15;
        const f16x8 v = *(const f16x8*)(hhF + (size_t)(ligBase + a)*HID + c4*8);
        *(f16x8*)&tbl[a*128 + ((c4 ^ (a & 15)) << 3)] = v;
    }

    // ---- tail (fp16) [128 rows][8 chunks]: temb(2)|smear(3)|0(3) -------
    for (int pe = tid; pe < 1024; pe += 256) {
        const int row = pe & 127, part = pe >> 7;
        U8h vh;
        if (part < 2) {
            const int r = node0 + (row >> 3);
            const int c = ecol[node0*KNN + row];
            int sbi = r*(KAT-1) + c - (r/KAT)*KAT - (r < c ? 1 : 0);
            const int tb = tbond[sbi];
            #pragma unroll
            for (int j = 0; j < 8; ++j)
                vh.a[j] = tembF[tb*TF + part*8 + j];
        } else if (part < 5) {
            const int r = node0 + (row >> 3);
            const int c = ecol[node0*KNN + row];
            float dx = x[3*r]-x[3*c], dy = x[3*r+1]-x[3*c+1], dz = x[3*r+2]-x[3*c+2];
            float dist = fminf(sqrtf(dx*dx+dy*dy+dz*dz), 4.0f);
            #pragma unroll
            for (int j = 0; j < 8; ++j) {
                int g = (part-2)*8 + j;
                float v = 0.0f;
                if (g < NG) {
                    float dd = dist - GS_OG[g];
                    v = __expf(GS_CF[g]*dd*dd);
                }
                vh.a[j] = (f16)v;
            }
        } else {
            #pragma unroll
            for (int j = 0; j < 8; ++j) vh.a[j] = (f16)0.0f;
        }
        *(f16x8*)&tailB[row*64 + ((part ^ (row & 7)) << 3)] = vh.v;
    }
    __syncthreads();                                    // bar1

    // ---- GEMM1: [128 x 320] @ [320 x 128], 1-deep W prefetch -----------
    f32x4 acc[8][2];
    #pragma unroll
    for (int rt = 0; rt < 8; ++rt) { acc[rt][0] = (f32x4){0,0,0,0}; acc[rt][1] = (f32x4){0,0,0,0}; }
    {
        #pragma unroll
        for (int s = 0; s < 10; ++s) {
            f16x8 nf0 = wf0, nf1 = wf1;
            if (s < 9) {
                nf0 = *(const f16x8*)(bF0 + 32*(s+1));
                nf1 = *(const f16x8*)(bF1 + 32*(s+1));
            }
            if (s < 4) {
                #pragma unroll
                for (int rt = 0; rt < 8; ++rt) {
                    const int aR = aBase + 2*rt + (lr >> 3);
                    const int c4 = s*4 + lh;
                    const int ad = aR*128 + ((c4 ^ (aR & 15)) << 3);
                    const f16x8 ah = *(const f16x8*)&tbl[ad];
                    acc[rt][0] = mfma16(ah, wf0, acc[rt][0]);
                    acc[rt][1] = mfma16(ah, wf1, acc[rt][1]);
                }
            } else if (s < 8) {
                #pragma unroll
                for (int rt = 0; rt < 8; ++rt) {
                    const int aC = (int)((rt < 4 ? (aColPk0 >> (rt*8))
                                                 : (aColPk1 >> ((rt-4)*8))) & 31u);
                    const int c4 = (s-4)*4 + lh;
                    const int ad = aC*128 + ((c4 ^ (aC & 15)) << 3);
                    const f16x8 ah = *(const f16x8*)&tbl[ad];
                    acc[rt][0] = mfma16(ah, wf0, acc[rt][0]);
                    acc[rt][1] = mfma16(ah, wf1, acc[rt][1]);
                }
            } else {
                #pragma unroll
                for (int rt = 0; rt < 8; ++rt) {
                    const int r = rt*16 + lr;
                    const int c = (s-8)*4 + lh;
                    const int ad = r*64 + ((c ^ (r & 7)) << 3);
                    const f16x8 ah = *(const f16x8*)&tailB[ad];
                    acc[rt][0] = mfma16(ah, wf0, acc[rt][0]);
                    acc[rt][1] = mfma16(ah, wf1, acc[rt][1]);
                }
            }
            wf0 = nf0; wf1 = nf1;
        }
    }

    // ---- bias + in-register LN partials --------------------------------
    {
        const float b10 = be1[colB0], b11 = be1[colB1];
        #pragma unroll
        for (int rt = 0; rt < 8; ++rt)
            #pragma unroll
            for (int j = 0; j < 4; ++j) { acc[rt][0][j] += b10; acc[rt][1][j] += b11; }
    }
    {
        #pragma unroll
        for (int rt = 0; rt < 8; ++rt) {
            float sv[4], qv[4];
            #pragma unroll
            for (int j = 0; j < 4; ++j) {
                const float a0 = acc[rt][0][j], a1 = acc[rt][1][j];
                sv[j] = a0 + a1; qv[j] = a0*a0 + a1*a1;
            }
            #pragma unroll
            for (int msk = 1; msk < 16; msk <<= 1) {
                #pragma unroll
                for (int j = 0; j < 4; ++j) {
                    sv[j] += __shfl_xor(sv[j], msk);
                    qv[j] += __shfl_xor(qv[j], msk);
                }
            }
            if (lr == 0) {
                #pragma unroll
                for (int j = 0; j < 4; ++j) {
                    const int row = rt*16 + 4*lh + j;
                    sStats[(row*4 + w)*2 + 0] = sv[j];
                    sStats[(row*4 + w)*2 + 1] = qv[j];
                }
            }
        }
    }
    __syncthreads();                                    // bar2

    if (tid < EPB) {
        const float4 a = *(const float4*)&sStats[tid*8];
        const float4 b = *(const float4*)&sStats[tid*8 + 4];
        const float st = a.x + a.z + b.x + b.z;
        const float qt = a.y + a.w + b.y + b.w;
        const float mu  = st * (1.0f/HID);
        const float var = qt * (1.0f/HID) - mu*mu;
        sMuInv[tid*2 + 0] = mu;
        sMuInv[tid*2 + 1] = rsqrtf(var + 1e-5f);
    }
    __syncthreads();                                    // bar3

    // ---- GEMM2 weight pointers + first fragments -----------------------
    const f16* c2F0 = W2T + (size_t)colB0*HID + lh*8;
    const f16* c2F1 = W2T + (size_t)colB1*HID + lh*8;
    f16x8 g2f0 = *(const f16x8*)c2F0, g2f1 = *(const f16x8*)c2F1;

    // ---- normalize + SiLU in regs, write fp16 acts to sB2 --------------
    {
        const float G0 = g1[colB0], G1s = g1[colB1];
        const float B0 = bt1[colB0], B1s = bt1[colB1];
        #pragma unroll
        for (int rt = 0; rt < 8; ++rt) {
            const int r0 = rt*16 + 4*lh;
            const float4 mi0 = *(const float4*)&sMuInv[r0*2];      // mu0,inv0,mu1,inv1
            const float4 mi1 = *(const float4*)&sMuInv[r0*2 + 4];  // mu2,inv2,mu3,inv3
            acc[rt][0][0] = siluf(fmaf((acc[rt][0][0]-mi0.x)*mi0.y, G0, B0));
            acc[rt][1][0] = siluf(fmaf((acc[rt][1][0]-mi0.x)*mi0.y, G1s, B1s));
            acc[rt][0][1] = siluf(fmaf((acc[rt][0][1]-mi0.z)*mi0.w, G0, B0));
            acc[rt][1][1] = siluf(fmaf((acc[rt][1][1]-mi0.z)*mi0.w, G1s, B1s));
            acc[rt][0][2] = siluf(fmaf((acc[rt][0][2]-mi1.x)*mi1.y, G0, B0));
            acc[rt][1][2] = siluf(fmaf((acc[rt][1][2]-mi1.x)*mi1.y, G1s, B1s));
            acc[rt][0][3] = siluf(fmaf((acc[rt][0][3]-mi1.z)*mi1.w, G0, B0));
            acc[rt][1][3] = siluf(fmaf((acc[rt][1][3]-mi1.z)*mi1.w, G1s, B1s));
        }
    }
    {
        #pragma unroll
        for (int rt = 0; rt < 8; ++rt) {
            #pragma unroll
            for (int hcol = 0; hcol < 2; ++hcol) {
                const int col = hcol ? colB1 : colB0;
                const int gch = col >> 3, cw = col & 7;
                #pragma unroll
                for (int j = 0; j < 4; ++j) {
                    const int row = rt*16 + 4*lh + j;
                    sB2[row*128 + ((gch ^ (row & 15)) << 3) + cw] =
                        (f16)acc[rt][hcol][j];
                }
            }
        }
    }
    __syncthreads();                                    // bar4

    // ---- GEMM2: [128 x 128] @ [128 x 128] ------------------------------
    f32x4 d[8][2];
    #pragma unroll
    for (int rt = 0; rt < 8; ++rt) { d[rt][0] = (f32x4){0,0,0,0}; d[rt][1] = (f32x4){0,0,0,0}; }
    {
        #pragma unroll
        for (int s = 0; s < 4; ++s) {
            f16x8 nf0 = g2f0, nf1 = g2f1;
            if (s < 3) {
                nf0 = *(const f16x8*)(c2F0 + 32*(s+1));
                nf1 = *(const f16x8*)(c2F1 + 32*(s+1));
            }
            #pragma unroll
            for (int rt = 0; rt < 8; ++rt) {
                const int rowL = rt*16 + lr;
                const int c4 = s*4 + lh;
                const f16x8 ah = *(const f16x8*)&sB2[rowL*128 + ((c4 ^ (rowL & 15)) << 3)];
                d[rt][0] = mfma16(ah, g2f0, d[rt][0]);
                d[rt][1] = mfma16(ah, g2f1, d[rt][1]);
            }
            g2f0 = nf0; g2f1 = nf1;
        }
    }

    // ---- SiLU in place (d becomes m) + attention gate ------------------
    {
        const float b20 = be2[colB0], b21 = be2[colB1];
        #pragma unroll
        for (int rt = 0; rt < 8; ++rt) {
            #pragma unroll
            for (int j = 0; j < 4; ++j) {
                d[rt][0][j] = siluf(d[rt][0][j] + b20);
                d[rt][1][j] = siluf(d[rt][1][j] + b21);
            }
        }
    }
    {
        const float wa0 = Watt[colB0], wa1 = Watt[colB1];
        float pa[8][4];
        #pragma unroll
        for (int rt = 0; rt < 8; ++rt)
            #pragma unroll
            for (int j = 0; j < 4; ++j)
                pa[rt][j] = d[rt][0][j]*wa0 + d[rt][1][j]*wa1;
        #pragma unroll
        for (int msk = 1; msk < 16; msk <<= 1) {
            #pragma unroll
            for (int rt = 0; rt < 8; ++rt)
                #pragma unroll
                for (int j = 0; j < 4; ++j)
                    pa[rt][j] += __shfl_xor(pa[rt][j], msk);
        }
        if (lr == 0) {
            #pragma unroll
            for (int rt = 0; rt < 8; ++rt)
                #pragma unroll
                for (int j = 0; j < 4; ++j)
                    sAP[w*128 + rt*16 + 4*lh + j] = pa[rt][j];
        }
    }
    __syncthreads();                                    // bar5
    if (tid < EPB)
        sAttv[tid] = sigf(sAP[tid] + sAP[128+tid] + sAP[256+tid] + sAP[384+tid] + batt[0]);
    __syncthreads();                                    // bar6

    // ---- gated aggregate -> sAgg (LDS, fp16, swizzled) -----------------
    #pragma unroll
    for (int rt = 0; rt < 8; ++rt) {
        float s0 = 0.0f, s1 = 0.0f;
        #pragma unroll
        for (int j = 0; j < 4; ++j) {
            const float av = sAttv[rt*16 + 4*lh + j];
            s0 += d[rt][0][j]*av;
            s1 += d[rt][1][j]*av;
        }
        s0 += __shfl_xor(s0, 16);
        s1 += __shfl_xor(s1, 16);
        if ((lh & 1) == 0) {
            const int nloc = 2*rt + (lh >> 1);
            sAgg[nloc*128 + (((colB0 >> 3) ^ nloc) << 3) + (colB0 & 7)] = (f16)(s0*0.2f);
            sAgg[nloc*128 + (((colB1 >> 3) ^ nloc) << 3) + (colB1 & 7)] = (f16)(s1*0.2f);
        }
    }
    __syncthreads();                                    // bar7

    // ================= fused node model (16 nodes of this block) ========
    // GEMM_n1: [16 x 256] @ [256 x 128]; A rows = nodes (lr), k = [hh|agg]
    const f16* n1F0 = WN1T + (size_t)colB0*256 + lh*8;
    const f16* n1F1 = WN1T + (size_t)colB1*256 + lh*8;
    f32x4 na0 = {0,0,0,0}, na1 = {0,0,0,0};
    {
        f16x8 nwf0 = *(const f16x8*)n1F0, nwf1 = *(const f16x8*)n1F1;
        #pragma unroll
        for (int s = 0; s < 8; ++s) {
            f16x8 nn0 = nwf0, nn1 = nwf1;
            if (s < 7) {
                nn0 = *(const f16x8*)(n1F0 + 32*(s+1));
                nn1 = *(const f16x8*)(n1F1 + 32*(s+1));
            }
            f16x8 ah;
            if (s < 4) {
                const int aR = aBase + lr;                // own node row
                const int c4 = s*4 + lh;
                ah = *(const f16x8*)&tbl[aR*128 + ((c4 ^ lr) << 3)];
            } else {
                const int c4 = (s-4)*4 + lh;
                ah = *(const f16x8*)&sAgg[lr*128 + ((c4 ^ lr) << 3)];
            }
            na0 = mfma16(ah, nwf0, na0);
            na1 = mfma16(ah, nwf1, na1);
            nwf0 = nn0; nwf1 = nn1;
        }
    }
    // bias + node-LN partials (16 rows)
    {
        const float b10 = bn1[colB0], b11 = bn1[colB1];
        float sv[4], qv[4];
        #pragma unroll
        for (int j = 0; j < 4; ++j) {
            na0[j] += b10; na1[j] += b11;
            sv[j] = na0[j] + na1[j];
            qv[j] = na0[j]*na0[j] + na1[j]*na1[j];
        }
        #pragma unroll
        for (int msk = 1; msk < 16; msk <<= 1) {
            #pragma unroll
            for (int j = 0; j < 4; ++j) {
                sv[j] += __shfl_xor(sv[j], msk);
                qv[j] += __shfl_xor(qv[j], msk);
            }
        }
        if (lr == 0) {
            #pragma unroll
            for (int j = 0; j < 4; ++j) {
                const int row = 4*lh + j;
                sStats[(row*4 + w)*2 + 0] = sv[j];
                sStats[(row*4 + w)*2 + 1] = qv[j];
            }
        }
    }
    __syncthreads();                                    // bar8
    if (tid < 16) {
        const float4 a = *(const float4*)&sStats[tid*8];
        const float4 b = *(const float4*)&sStats[tid*8 + 4];
        const float st = a.x + a.z + b.x + b.z;
        const float qt = a.y + a.w + b.y + b.w;
        const float mu  = st * (1.0f/HID);
        const float var = qt * (1.0f/HID) - mu*mu;
        sMuInv[tid*2 + 0] = mu;
        sMuInv[tid*2 + 1] = rsqrtf(var + 1e-5f);
    }
    __syncthreads();                                    // bar9

    // node normalize + SiLU -> sY (fp16, swizzled) -----------------------
    const f16* n2F0 = WN2T + (size_t)colB0*HID + lh*8;
    const f16* n2F1 = WN2T + (size_t)colB1*HID + lh*8;
    f16x8 n2wf0 = *(const f16x8*)n2F0, n2wf1 = *(const f16x8*)n2F1;
    {
        const float G0 = gn[colB0], G1s = gn[colB1];
        const float B0 = btn[colB0], B1s = btn[colB1];
        #pragma unroll
        for (int j = 0; j < 4; ++j) {
            const int row = 4*lh + j;
            const float mu  = sMuInv[row*2 + 0];
            const float inv = sMuInv[row*2 + 1];
            const float y0 = siluf(fmaf((na0[j]-mu)*inv, G0, B0));
            const float y1 = siluf(fmaf((na1[j]-mu)*inv, G1s, B1s));
            sY[row*128 + (((colB0 >> 3) ^ row) << 3) + (colB0 & 7)] = (f16)y0;
            sY[row*128 + (((colB1 >> 3) ^ row) << 3) + (colB1 & 7)] = (f16)y1;
        }
    }
    __syncthreads();                                    // bar10

    // GEMM_n2: [16 x 128] @ [128 x 128] ----------------------------------
    f32x4 nd0 = {0,0,0,0}, nd1 = {0,0,0,0};
    {
        #pragma unroll
        for (int s = 0; s < 4; ++s) {
            f16x8 nn0 = n2wf0, nn1 = n2wf1;
            if (s < 3) {
                nn0 = *(const f16x8*)(n2F0 + 32*(s+1));
                nn1 = *(const f16x8*)(n2F1 + 32*(s+1));
            }
            const int c4 = s*4 + lh;
            const f16x8 ah = *(const f16x8*)&sY[lr*128 + ((c4 ^ lr) << 3)];
            nd0 = mfma16(ah, n2wf0, nd0);
            nd1 = mfma16(ah, n2wf1, nd1);
            n2wf0 = nn0; n2wf1 = nn1;
        }
    }

    // bias + residual -> hh (f32) and hhF (f16) --------------------------
    {
        const float b20 = bn2[colB0], b21 = bn2[colB1];
        #pragma unroll
        for (int j = 0; j < 4; ++j) {
            const int node = node0 + 4*lh + j;
            const size_t i0 = (size_t)node*HID + colB0;
            const size_t i1 = (size_t)node*HID + colB1;
            const float v0 = hh[i0] + nd0[j] + b20;
            const float v1 = hh[i1] + nd1[j] + b21;
            hh[i0] = v0; hh[i1] = v1;
            hhF[i0] = (f16)v0; hhF[i1] = (f16)v1;
        }
    }
}

// ---------------------------------------------------------------- output head
__global__ __launch_bounds__(HID) void out_k(
    const float* __restrict__ hh, const float* __restrict__ Woe,
    const float* __restrict__ boe, const float* __restrict__ Wf,
    const float* __restrict__ bf, float* __restrict__ out)
{
    __shared__ float sH[HID];
    const int lig = blockIdx.x, tid = threadIdx.x;
    float s = 0.0f;
    const float* base = hh + (size_t)lig*KAT*HID + tid;
    #pragma unroll 8
    for (int a = 0; a < KAT; ++a) s += base[a*HID];
    sH[tid] = s * (1.0f/KAT);
    __syncthreads();

    float contrib = 0.0f;
    if (tid < OUTF) {
        float p = boe[tid];
        #pragma unroll 4
        for (int i = 0; i < HID; ++i)
            p = fmaf(sH[i], Woe[i*OUTF + tid], p);
        contrib = p * Wf[tid];
    }
    #pragma unroll
    for (int m = 1; m < 64; m <<= 1) contrib += __shfl_xor(contrib, m);
    if (tid == 0) out[lig] = contrib + bf[0];
}

// ---------------------------------------------------------------- launch
extern "C" void kernel_launch(void* const* d_in, const int* in_sizes, int n_in,
                              void* d_out, int out_size, void* d_ws, size_t ws_size,
                              hipStream_t stream)
{
    (void)in_sizes; (void)n_in; (void)out_size; (void)ws_size;
    const float* x    = (const float*)d_in[0];
    const float* h    = (const float*)d_in[1];
    const int*   t    = (const int*)d_in[2];
    const int*   edges= (const int*)d_in[3];
    const int*   tb   = (const int*)d_in[4];
    const float* temb = (const float*)d_in[8];
    const float* Win  = (const float*)d_in[9];
    const float* bin  = (const float*)d_in[10];
    const float* We1  = (const float*)d_in[11];
    const float* be1  = (const float*)d_in[12];
    const float* g1   = (const float*)d_in[13];
    const float* bt1  = (const float*)d_in[14];
    const float* We2  = (const float*)d_in[15];
    const float* be2  = (const float*)d_in[16];
    const float* Watt = (const float*)d_in[17];
    const float* batt = (const float*)d_in[18];
    const float* Wn1  = (const float*)d_in[19];
    const float* bn1  = (const float*)d_in[20];
    const float* g2   = (const float*)d_in[21];
    const float* bt2  = (const float*)d_in[22];
    const float* Wn2  = (const float*)d_in[23];
    const float* bn2  = (const float*)d_in[24];
    const float* Woe  = (const float*)d_in[25];
    const float* boe  = (const float*)d_in[26];
    const float* Wf   = (const float*)d_in[27];
    const float* bf   = (const float*)d_in[28];
    float* out = (float*)d_out;

    char* wsb = (char*)d_ws;
    float* hh  = (float*)(wsb);                        // 16 MB
    f16* hhF   = (f16*)(wsb + ((size_t)16<<20));       // 8 MB
    f16* tembF = (f16*)(wsb + ((size_t)24<<20));
    f16* W1T   = tembF + PREP_TEMB;
    f16* W2T   = W1T + PREP_W1;
    f16* WN1T  = W2T + PREP_W2;
    f16* WN2T  = WN1T + PREP_WN1;

    prep_k<<<(PREP_TOT + 255)/256, 256, 0, stream>>>(
        temb, We1, We2, Wn1, Wn2, tembF, W1T, W2T, WN1T, WN2T);

    embed_k<<<NNODES/8, 256, 0, stream>>>(h, t, temb, Win, bin, hh, hhF);

    for (int l = 0; l < 4; ++l) {
        fused_k<<<NNODES/NPB, 256, 0, stream>>>(
            hh, hhF, x, edges + NEDGES, tb, tembF,
            W1T + (size_t)l*128*K1, W2T + (size_t)l*128*128,
            WN1T + (size_t)l*128*256, WN2T + (size_t)l*128*128,
            be1 + l*HID, g1 + l*HID, bt1 + l*HID, be2 + l*HID,
            Watt + l*HID, batt + l,
            bn1 + l*HID, g2 + l*HID, bt2 + l*HID, bn2 + l*HID);
    }
    out_k<<<NLIG, HID, 0, stream>>>(hh, Woe, boe, Wf, bf, out);
}

// Round 18
// 455.185 us; speedup vs baseline: 1.3248x; 1.0029x over previous
//
#include <hip/hip_runtime.h>
#include <math.h>

#define NNODES 32768
#define NLIG   1024
#define KAT    32
#define KNN    8
#define NEDGES (NNODES*KNN)
#define HID    128
#define TF     16
#define NG     20
#define OUTF   64

#define NPB    16           // nodes per edge-block
#define EPB    128          // edges per edge-block
#define K1     320          // padded GEMM1 K (292 -> 320)

typedef unsigned short u16;
typedef _Float16 f16;
typedef __attribute__((__ext_vector_type__(8))) _Float16 f16x8;
typedef __attribute__((__ext_vector_type__(4))) float f32x4;

union U8h { f16 a[8]; f16x8 v; };

// Gaussian smearing constants: og[g] = 5^(g/19)-1, coeff = -0.5/diff^2
__device__ const float GS_OG[20] = {
    0.0f, 0.0883984f, 0.1845966f, 0.2893285f, 0.4033028f,
    0.5273539f, 0.6623701f, 0.8093209f, 0.9692606f, 1.1433389f,
    1.3328075f, 1.5390240f, 1.7634662f, 2.0077560f, 2.2736369f,
    2.5630207f, 2.8779861f, 3.2207938f, 3.5939058f, 4.0f };
__device__ const float GS_CF[20] = {
    -63.9853f, -63.9853f, -54.0303f, -45.5840f, -38.4908f,
    -32.4913f, -27.4283f, -23.1540f, -19.5460f, -16.4999f,
    -13.9282f, -11.7577f, -9.92569f, -8.37837f, -7.07287f,
    -5.97065f, -5.04016f, -4.25470f, -3.59163f, -3.03191f };

__device__ __forceinline__ float siluf(float v) {
    return __fdividef(v, 1.0f + __expf(-v));
}
__device__ __forceinline__ float sigf(float v) {
    return __fdividef(1.0f, 1.0f + __expf(-v));
}
__device__ __forceinline__ f32x4 mfma16(f16x8 a, f16x8 b, f32x4 c) {
    return __builtin_amdgcn_mfma_f32_16x16x32_f16(a, b, c, 0, 0, 0);
}

// ---------------------------------------------------------------- prep (fp16 single)
#define PREP_TEMB 16000
#define PREP_W1   (4*128*K1)       // 163840
#define PREP_W2   (4*128*128)      // 65536
#define PREP_WN1  (4*128*256)      // 131072
#define PREP_WN2  (4*128*128)      // 65536
#define PREP_TOT  (PREP_TEMB+PREP_W1+PREP_W2+PREP_WN1+PREP_WN2)

__global__ __launch_bounds__(256) void prep_k(
    const float* __restrict__ temb, const float* __restrict__ We1,
    const float* __restrict__ We2,  const float* __restrict__ Wn1,
    const float* __restrict__ Wn2,
    f16* __restrict__ tembF,
    f16* __restrict__ W1T, f16* __restrict__ W2T,
    f16* __restrict__ WN1T, f16* __restrict__ WN2T)
{
    int i = blockIdx.x*256 + threadIdx.x;
    if (i >= PREP_TOT) return;
    float v; f16* dst; int di;
    if (i < PREP_TEMB) {
        v = temb[i]; dst = tembF; di = i;
    } else if (i < PREP_TEMB + PREP_W1) {
        int j = i - PREP_TEMB; di = j; dst = W1T;
        int l = j / (128*K1); int r = j - l*(128*K1);
        int col = r / K1, k = r - col*K1;
        v = (k < 292) ? We1[(size_t)l*292*128 + (size_t)k*128 + col] : 0.0f;
    } else if (i < PREP_TEMB + PREP_W1 + PREP_W2) {
        int j = i - PREP_TEMB - PREP_W1; di = j; dst = W2T;
        int l = j >> 14; int r = j & 16383;
        int col = r >> 7, k = r & 127;
        v = We2[(size_t)l*16384 + (size_t)k*128 + col];
    } else if (i < PREP_TEMB + PREP_W1 + PREP_W2 + PREP_WN1) {
        int j = i - PREP_TEMB - PREP_W1 - PREP_W2; di = j; dst = WN1T;
        int l = j >> 15; int r = j & 32767;
        int col = r >> 8, k = r & 255;
        v = Wn1[(size_t)l*32768 + (size_t)k*128 + col];
    } else {
        int j = i - PREP_TEMB - PREP_W1 - PREP_W2 - PREP_WN1; di = j; dst = WN2T;
        int l = j >> 14; int r = j & 16383;
        int col = r >> 7, k = r & 127;
        v = Wn2[(size_t)l*16384 + (size_t)k*128 + col];
    }
    dst[di] = (f16)v;
}

// ---------------------------------------------------------------- tail prep
// Layer-invariant edge features (temb[t_bond] | smear | pad), computed ONCE
// into each block's exact swizzled 16KB LDS image. fused_k just memcpys it.
__global__ __launch_bounds__(256) void tailprep_k(
    const float* __restrict__ x,
    const int* __restrict__ ecol, const int* __restrict__ tbond,
    const f16* __restrict__ tembF, f16* __restrict__ tailG)
{
    const int node0 = blockIdx.x * NPB;
    const int tid = threadIdx.x;
    f16* dst = tailG + (size_t)blockIdx.x * 8192;
    for (int pe = tid; pe < 1024; pe += 256) {
        const int row = pe & 127, part = pe >> 3 >> 4;   // pe>>7
        U8h vh;
        if (part < 2) {
            const int r = node0 + (row >> 3);
            const int c = ecol[node0*KNN + row];
            int sbi = r*(KAT-1) + c - (r/KAT)*KAT - (r < c ? 1 : 0);
            const int tb = tbond[sbi];
            #pragma unroll
            for (int j = 0; j < 8; ++j)
                vh.a[j] = tembF[tb*TF + part*8 + j];
        } else if (part < 5) {
            const int r = node0 + (row >> 3);
            const int c = ecol[node0*KNN + row];
            float dx = x[3*r]-x[3*c], dy = x[3*r+1]-x[3*c+1], dz = x[3*r+2]-x[3*c+2];
            float dist = fminf(sqrtf(dx*dx+dy*dy+dz*dz), 4.0f);
            #pragma unroll
            for (int j = 0; j < 8; ++j) {
                int g = (part-2)*8 + j;
                float v = 0.0f;
                if (g < NG) {
                    float dd = dist - GS_OG[g];
                    v = __expf(GS_CF[g]*dd*dd);
                }
                vh.a[j] = (f16)v;
            }
        } else {
            #pragma unroll
            for (int j = 0; j < 8; ++j) vh.a[j] = (f16)0.0f;
        }
        *(f16x8*)&dst[row*64 + ((part ^ (row & 7)) << 3)] = vh.v;
    }
}

// ---------------------------------------------------------------- embed (8 nodes/block)
__global__ __launch_bounds__(256) void embed_k(
    const float* __restrict__ h, const int* __restrict__ t,
    const float* __restrict__ temb, const float* __restrict__ Win,
    const float* __restrict__ bin, float* __restrict__ hh,
    f16* __restrict__ hhF)
{
    __shared__ float sIn[8][32];
    const int tid = threadIdx.x;
    {
        const int n = tid >> 5, i = tid & 31;
        const int node = blockIdx.x*8 + n;
        sIn[n][i] = (i < TF) ? h[node*TF + i] : temb[t[node]*TF + (i-TF)];
    }
    __syncthreads();
    const int sub = tid >> 7, col = tid & 127;
    float acc[4];
    const float b = bin[col];
    acc[0]=acc[1]=acc[2]=acc[3]=b;
    #pragma unroll 8
    for (int i = 0; i < 32; ++i) {
        const float wv = Win[i*HID + col];
        acc[0] = fmaf(sIn[sub][i],   wv, acc[0]);
        acc[1] = fmaf(sIn[2+sub][i], wv, acc[1]);
        acc[2] = fmaf(sIn[4+sub][i], wv, acc[2]);
        acc[3] = fmaf(sIn[6+sub][i], wv, acc[3]);
    }
    #pragma unroll
    for (int nn = 0; nn < 4; ++nn) {
        const size_t idx = (size_t)(blockIdx.x*8 + nn*2 + sub)*HID + col;
        hh[idx] = acc[nn];
        hhF[idx] = (f16)acc[nn];
    }
}

// ---------------------------------------------------------------- fused edge+node
// M=128 edges (16 nodes) per block. Edge MLP -> agg in LDS -> node MLP fused.
// Tail features loaded from precomputed tailG (linear 16KB coalesced copy).
__global__ __launch_bounds__(256, 3) void fused_k(
    float* __restrict__ hh, f16* __restrict__ hhF,
    const int* __restrict__ ecol, const f16* __restrict__ tailG,
    const f16* __restrict__ W1T, const f16* __restrict__ W2T,
    const f16* __restrict__ WN1T, const f16* __restrict__ WN2T,
    const float* __restrict__ be1, const float* __restrict__ g1,
    const float* __restrict__ bt1, const float* __restrict__ be2,
    const float* __restrict__ Watt, const float* __restrict__ batt,
    const float* __restrict__ bn1, const float* __restrict__ gn,
    const float* __restrict__ btn, const float* __restrict__ bn2)
{
    // LDS (46592 B):
    //  [0,8192)       tbl (32 atoms x 128 f16)  -- LIVE until node GEMM_n1
    //  [8192,40960)   sB2 (128x128 f16, 32 KB); tailB (16 KB) aliases its
    //                 low half before bar2; sAgg[16][128] f16 at +8192 and
    //                 sY[16][128] f16 at +12288 alias it after GEMM2 reads.
    //  [40960,45056)  sStats (128 x 4 waves x f32x2); sAP (512 f32) aliases
    //  [45056,46080)  sMuInv (128 x f32x2)
    //  [46080,46592)  sAttv (128 f32)
    __shared__ __align__(16) char smem[46592];
    f16*   tbl   = (f16*)(smem);
    f16*   sB2   = (f16*)(smem + 8192);
    f16*   tailB = (f16*)(smem + 8192);
    f16*   sAgg  = (f16*)(smem + 8192);
    f16*   sY    = (f16*)(smem + 12288);
    float* sStats= (float*)(smem + 40960);
    float* sAP   = (float*)(smem + 40960);
    float* sMuInv= (float*)(smem + 45056);
    float* sAttv = (float*)(smem + 46080);

    const int tid = threadIdx.x;
    const int node0 = blockIdx.x * NPB;
    const int ligBase = node0 & ~31;
    const int aBase   = node0 & 31;      // 0 or 16
    const int w = tid >> 6, lane = tid & 63, lr = lane & 15, lh = lane >> 4;
    const int colB0 = w*32 + lr, colB1 = colB0 + 16;

    // ---- per-lane col atom ids, packed 8x8b into 2 u32 -----------------
    unsigned aColPk0 = 0, aColPk1 = 0;
    #pragma unroll
    for (int rt = 0; rt < 4; ++rt)
        aColPk0 |= (unsigned)(ecol[node0*KNN + rt*16 + lr] & 31) << (rt*8);
    #pragma unroll
    for (int rt = 0; rt < 4; ++rt)
        aColPk1 |= (unsigned)(ecol[node0*KNN + (4+rt)*16 + lr] & 31) << (rt*8);

    // ---- GEMM1 weight pointers + first fragments -----------------------
    const f16* bF0 = W1T + (size_t)colB0*K1 + lh*8;
    const f16* bF1 = W1T + (size_t)colB1*K1 + lh*8;
    f16x8 wf0 = *(const f16x8*)bF0, wf1 = *(const f16x8*)bF1;

    // ---- stage ligand hh table (32 atoms x 16 chunks) ------------------
    for (int idx = tid; idx < 512; idx += 256) {
        const int a = idx >> 4, c4 = idx & 15;
        const f16x8 v = *(const f16x8*)(hhF + (size_t)(ligBase + a)*HID + c4*8);
        *(f16x8*)&tbl[a*128 + ((c4 ^ (a & 15)) << 3)] = v;
    }

    // ---- tail: linear coalesced copy of precomputed 16KB image ---------
    {
        const f16* tsrc = tailG + (size_t)blockIdx.x * 8192;
        #pragma unroll
        for (int it = 0; it < 4; ++it) {
            const int g = tid + it*256;
            *(f16x8*)&tailB[g*8] = *(const f16x8*)&tsrc[g*8];
        }
    }
    __syncthreads();                                    // bar1

    // ---- GEMM1: [128 x 320] @ [320 x 128], 1-deep W prefetch -----------
    f32x4 acc[8][2];
    #pragma unroll
    for (int rt = 0; rt < 8; ++rt) { acc[rt][0] = (f32x4){0,0,0,0}; acc[rt][1] = (f32x4){0,0,0,0}; }
    {
        #pragma unroll
        for (int s = 0; s < 10; ++s) {
            f16x8 nf0 = wf0, nf1 = wf1;
            if (s < 9) {
                nf0 = *(const f16x8*)(bF0 + 32*(s+1));
                nf1 = *(const f16x8*)(bF1 + 32*(s+1));
            }
            if (s < 4) {
                #pragma unroll
                for (int rt = 0; rt < 8; ++rt) {
                    const int aR = aBase + 2*rt + (lr >> 3);
                    const int c4 = s*4 + lh;
                    const int ad = aR*128 + ((c4 ^ (aR & 15)) << 3);
                    const f16x8 ah = *(const f16x8*)&tbl[ad];
                    acc[rt][0] = mfma16(ah, wf0, acc[rt][0]);
                    acc[rt][1] = mfma16(ah, wf1, acc[rt][1]);
                }
            } else if (s < 8) {
                #pragma unroll
                for (int rt = 0; rt < 8; ++rt) {
                    const int aC = (int)((rt < 4 ? (aColPk0 >> (rt*8))
                                                 : (aColPk1 >> ((rt-4)*8))) & 31u);
                    const int c4 = (s-4)*4 + lh;
                    const int ad = aC*128 + ((c4 ^ (aC & 15)) << 3);
                    const f16x8 ah = *(const f16x8*)&tbl[ad];
                    acc[rt][0] = mfma16(ah, wf0, acc[rt][0]);
                    acc[rt][1] = mfma16(ah, wf1, acc[rt][1]);
                }
            } else {
                #pragma unroll
                for (int rt = 0; rt < 8; ++rt) {
                    const int r = rt*16 + lr;
                    const int c = (s-8)*4 + lh;
                    const int ad = r*64 + ((c ^ (r & 7)) << 3);
                    const f16x8 ah = *(const f16x8*)&tailB[ad];
                    acc[rt][0] = mfma16(ah, wf0, acc[rt][0]);
                    acc[rt][1] = mfma16(ah, wf1, acc[rt][1]);
                }
            }
            wf0 = nf0; wf1 = nf1;
        }
    }

    // ---- bias + in-register LN partials --------------------------------
    {
        const float b10 = be1[colB0], b11 = be1[colB1];
        #pragma unroll
        for (int rt = 0; rt < 8; ++rt)
            #pragma unroll
            for (int j = 0; j < 4; ++j) { acc[rt][0][j] += b10; acc[rt][1][j] += b11; }
    }
    {
        #pragma unroll
        for (int rt = 0; rt < 8; ++rt) {
            float sv[4], qv[4];
            #pragma unroll
            for (int j = 0; j < 4; ++j) {
                const float a0 = acc[rt][0][j], a1 = acc[rt][1][j];
                sv[j] = a0 + a1; qv[j] = a0*a0 + a1*a1;
            }
            #pragma unroll
            for (int msk = 1; msk < 16; msk <<= 1) {
                #pragma unroll
                for (int j = 0; j < 4; ++j) {
                    sv[j] += __shfl_xor(sv[j], msk);
                    qv[j] += __shfl_xor(qv[j], msk);
                }
            }
            if (lr == 0) {
                #pragma unroll
                for (int j = 0; j < 4; ++j) {
                    const int row = rt*16 + 4*lh + j;
                    sStats[(row*4 + w)*2 + 0] = sv[j];
                    sStats[(row*4 + w)*2 + 1] = qv[j];
                }
            }
        }
    }
    __syncthreads();                                    // bar2

    if (tid < EPB) {
        const float4 a = *(const float4*)&sStats[tid*8];
        const float4 b = *(const float4*)&sStats[tid*8 + 4];
        const float st = a.x + a.z + b.x + b.z;
        const float qt = a.y + a.w + b.y + b.w;
        const float mu  = st * (1.0f/HID);
        const float var = qt * (1.0f/HID) - mu*mu;
        sMuInv[tid*2 + 0] = mu;
        sMuInv[tid*2 + 1] = rsqrtf(var + 1e-5f);
    }
    __syncthreads();                                    // bar3

    // ---- GEMM2 weight pointers + first fragments -----------------------
    const f16* c2F0 = W2T + (size_t)colB0*HID + lh*8;
    const f16* c2F1 = W2T + (size_t)colB1*HID + lh*8;
    f16x8 g2f0 = *(const f16x8*)c2F0, g2f1 = *(const f16x8*)c2F1;

    // ---- normalize + SiLU in regs, write fp16 acts to sB2 --------------
    {
        const float G0 = g1[colB0], G1s = g1[colB1];
        const float B0 = bt1[colB0], B1s = bt1[colB1];
        #pragma unroll
        for (int rt = 0; rt < 8; ++rt) {
            const int r0 = rt*16 + 4*lh;
            const float4 mi0 = *(const float4*)&sMuInv[r0*2];      // mu0,inv0,mu1,inv1
            const float4 mi1 = *(const float4*)&sMuInv[r0*2 + 4];  // mu2,inv2,mu3,inv3
            acc[rt][0][0] = siluf(fmaf((acc[rt][0][0]-mi0.x)*mi0.y, G0, B0));
            acc[rt][1][0] = siluf(fmaf((acc[rt][1][0]-mi0.x)*mi0.y, G1s, B1s));
            acc[rt][0][1] = siluf(fmaf((acc[rt][0][1]-mi0.z)*mi0.w, G0, B0));
            acc[rt][1][1] = siluf(fmaf((acc[rt][1][1]-mi0.z)*mi0.w, G1s, B1s));
            acc[rt][0][2] = siluf(fmaf((acc[rt][0][2]-mi1.x)*mi1.y, G0, B0));
            acc[rt][1][2] = siluf(fmaf((acc[rt][1][2]-mi1.x)*mi1.y, G1s, B1s));
            acc[rt][0][3] = siluf(fmaf((acc[rt][0][3]-mi1.z)*mi1.w, G0, B0));
            acc[rt][1][3] = siluf(fmaf((acc[rt][1][3]-mi1.z)*mi1.w, G1s, B1s));
        }
    }
    {
        #pragma unroll
        for (int rt = 0; rt < 8; ++rt) {
            #pragma unroll
            for (int hcol = 0; hcol < 2; ++hcol) {
                const int col = hcol ? colB1 : colB0;
                const int gch = col >> 3, cw = col & 7;
                #pragma unroll
                for (int j = 0; j < 4; ++j) {
                    const int row = rt*16 + 4*lh + j;
                    sB2[row*128 + ((gch ^ (row & 15)) << 3) + cw] =
                        (f16)acc[rt][hcol][j];
                }
            }
        }
    }
    __syncthreads();                                    // bar4

    // ---- GEMM2: [128 x 128] @ [128 x 128] ------------------------------
    f32x4 d[8][2];
    #pragma unroll
    for (int rt = 0; rt < 8; ++rt) { d[rt][0] = (f32x4){0,0,0,0}; d[rt][1] = (f32x4){0,0,0,0}; }
    {
        #pragma unroll
        for (int s = 0; s < 4; ++s) {
            f16x8 nf0 = g2f0, nf1 = g2f1;
            if (s < 3) {
                nf0 = *(const f16x8*)(c2F0 + 32*(s+1));
                nf1 = *(const f16x8*)(c2F1 + 32*(s+1));
            }
            #pragma unroll
            for (int rt = 0; rt < 8; ++rt) {
                const int rowL = rt*16 + lr;
                const int c4 = s*4 + lh;
                const f16x8 ah = *(const f16x8*)&sB2[rowL*128 + ((c4 ^ (rowL & 15)) << 3)];
                d[rt][0] = mfma16(ah, g2f0, d[rt][0]);
                d[rt][1] = mfma16(ah, g2f1, d[rt][1]);
            }
            g2f0 = nf0; g2f1 = nf1;
        }
    }

    // ---- SiLU in place (d becomes m) + attention gate ------------------
    {
        const float b20 = be2[colB0], b21 = be2[colB1];
        #pragma unroll
        for (int rt = 0; rt < 8; ++rt) {
            #pragma unroll
            for (int j = 0; j < 4; ++j) {
                d[rt][0][j] = siluf(d[rt][0][j] + b20);
                d[rt][1][j] = siluf(d[rt][1][j] + b21);
            }
        }
    }
    {
        const float wa0 = Watt[colB0], wa1 = Watt[colB1];
        float pa[8][4];
        #pragma unroll
        for (int rt = 0; rt < 8; ++rt)
            #pragma unroll
            for (int j = 0; j < 4; ++j)
                pa[rt][j] = d[rt][0][j]*wa0 + d[rt][1][j]*wa1;
        #pragma unroll
        for (int msk = 1; msk < 16; msk <<= 1) {
            #pragma unroll
            for (int rt = 0; rt < 8; ++rt)
                #pragma unroll
                for (int j = 0; j < 4; ++j)
                    pa[rt][j] += __shfl_xor(pa[rt][j], msk);
        }
        if (lr == 0) {
            #pragma unroll
            for (int rt = 0; rt < 8; ++rt)
                #pragma unroll
                for (int j = 0; j < 4; ++j)
                    sAP[w*128 + rt*16 + 4*lh + j] = pa[rt][j];
        }
    }
    __syncthreads();                                    // bar5
    if (tid < EPB)
        sAttv[tid] = sigf(sAP[tid] + sAP[128+tid] + sAP[256+tid] + sAP[384+tid] + batt[0]);
    __syncthreads();                                    // bar6

    // ---- gated aggregate -> sAgg (LDS, fp16, swizzled) -----------------
    #pragma unroll
    for (int rt = 0; rt < 8; ++rt) {
        float s0 = 0.0f, s1 = 0.0f;
        #pragma unroll
        for (int j = 0; j < 4; ++j) {
            const float av = sAttv[rt*16 + 4*lh + j];
            s0 += d[rt][0][j]*av;
            s1 += d[rt][1][j]*av;
        }
        s0 += __shfl_xor(s0, 16);
        s1 += __shfl_xor(s1, 16);
        if ((lh & 1) == 0) {
            const int nloc = 2*rt + (lh >> 1);
            sAgg[nloc*128 + (((colB0 >> 3) ^ nloc) << 3) + (colB0 & 7)] = (f16)(s0*0.2f);
            sAgg[nloc*128 + (((colB1 >> 3) ^ nloc) << 3) + (colB1 & 7)] = (f16)(s1*0.2f);
        }
    }
    __syncthreads();                                    // bar7

    // ================= fused node model (16 nodes of this block) ========
    // GEMM_n1: [16 x 256] @ [256 x 128]; A rows = nodes (lr), k = [hh|agg]
    const f16* n1F0 = WN1T + (size_t)colB0*256 + lh*8;
    const f16* n1F1 = WN1T + (size_t)colB1*256 + lh*8;
    f32x4 na0 = {0,0,0,0}, na1 = {0,0,0,0};
    {
        f16x8 nwf0 = *(const f16x8*)n1F0, nwf1 = *(const f16x8*)n1F1;
        #pragma unroll
        for (int s = 0; s < 8; ++s) {
            f16x8 nn0 = nwf0, nn1 = nwf1;
            if (s < 7) {
                nn0 = *(const f16x8*)(n1F0 + 32*(s+1));
                nn1 = *(const f16x8*)(n1F1 + 32*(s+1));
            }
            f16x8 ah;
            if (s < 4) {
                const int aR = aBase + lr;                // own node row
                const int c4 = s*4 + lh;
                ah = *(const f16x8*)&tbl[aR*128 + ((c4 ^ lr) << 3)];
            } else {
                const int c4 = (s-4)*4 + lh;
                ah = *(const f16x8*)&sAgg[lr*128 + ((c4 ^ lr) << 3)];
            }
            na0 = mfma16(ah, nwf0, na0);
            na1 = mfma16(ah, nwf1, na1);
            nwf0 = nn0; nwf1 = nn1;
        }
    }
    // bias + node-LN partials (16 rows)
    {
        const float b10 = bn1[colB0], b11 = bn1[colB1];
        float sv[4], qv[4];
        #pragma unroll
        for (int j = 0; j < 4; ++j) {
            na0[j] += b10; na1[j] += b11;
            sv[j] = na0[j] + na1[j];
            qv[j] = na0[j]*na0[j] + na1[j]*na1[j];
        }
        #pragma unroll
        for (int msk = 1; msk < 16; msk <<= 1) {
            #pragma unroll
            for (int j = 0; j < 4; ++j) {
                sv[j] += __shfl_xor(sv[j], msk);
                qv[j] += __shfl_xor(qv[j], msk);
            }
        }
        if (lr == 0) {
            #pragma unroll
            for (int j = 0; j < 4; ++j) {
                const int row = 4*lh + j;
                sStats[(row*4 + w)*2 + 0] = sv[j];
                sStats[(row*4 + w)*2 + 1] = qv[j];
            }
        }
    }
    __syncthreads();                                    // bar8
    if (tid < 16) {
        const float4 a = *(const float4*)&sStats[tid*8];
        const float4 b = *(const float4*)&sStats[tid*8 + 4];
        const float st = a.x + a.z + b.x + b.z;
        const float qt = a.y + a.w + b.y + b.w;
        const float mu  = st * (1.0f/HID);
        const float var = qt * (1.0f/HID) - mu*mu;
        sMuInv[tid*2 + 0] = mu;
        sMuInv[tid*2 + 1] = rsqrtf(var + 1e-5f);
    }
    __syncthreads();                                    // bar9

    // node normalize + SiLU -> sY (fp16, swizzled) -----------------------
    const f16* n2F0 = WN2T + (size_t)colB0*HID + lh*8;
    const f16* n2F1 = WN2T + (size_t)colB1*HID + lh*8;
    f16x8 n2wf0 = *(const f16x8*)n2F0, n2wf1 = *(const f16x8*)n2F1;
    {
        const float G0 = gn[colB0], G1s = gn[colB1];
        const float B0 = btn[colB0], B1s = btn[colB1];
        #pragma unroll
        for (int j = 0; j < 4; ++j) {
            const int row = 4*lh + j;
            const float mu  = sMuInv[row*2 + 0];
            const float inv = sMuInv[row*2 + 1];
            const float y0 = siluf(fmaf((na0[j]-mu)*inv, G0, B0));
            const float y1 = siluf(fmaf((na1[j]-mu)*inv, G1s, B1s));
            sY[row*128 + (((colB0 >> 3) ^ row) << 3) + (colB0 & 7)] = (f16)y0;
            sY[row*128 + (((colB1 >> 3) ^ row) << 3) + (colB1 & 7)] = (f16)y1;
        }
    }
    __syncthreads();                                    // bar10

    // GEMM_n2: [16 x 128] @ [128 x 128] ----------------------------------
    f32x4 nd0 = {0,0,0,0}, nd1 = {0,0,0,0};
    {
        #pragma unroll
        for (int s = 0; s < 4; ++s) {
            f16x8 nn0 = n2wf0, nn1 = n2wf1;
            if (s < 3) {
                nn0 = *(const f16x8*)(n2F0 + 32*(s+1));
                nn1 = *(const f16x8*)(n2F1 + 32*(s+1));
            }
            const int c4 = s*4 + lh;
            const f16x8 ah = *(const f16x8*)&sY[lr*128 + ((c4 ^ lr) << 3)];
            nd0 = mfma16(ah, n2wf0, nd0);
            nd1 = mfma16(ah, n2wf1, nd1);
            n2wf0 = nn0; n2wf1 = nn1;
        }
    }

    // bias + residual -> hh (f32) and hhF (f16) --------------------------
    {
        const float b20 = bn2[colB0], b21 = bn2[colB1];
        #pragma unroll
        for (int j = 0; j < 4; ++j) {
            const int node = node0 + 4*lh + j;
            const size_t i0 = (size_t)node*HID + colB0;
            const size_t i1 = (size_t)node*HID + colB1;
            const float v0 = hh[i0] + nd0[j] + b20;
            const float v1 = hh[i1] + nd1[j] + b21;
            hh[i0] = v0; hh[i1] = v1;
            hhF[i0] = (f16)v0; hhF[i1] = (f16)v1;
        }
    }
}

// ---------------------------------------------------------------- output head
__global__ __launch_bounds__(HID) void out_k(
    const float* __restrict__ hh, const float* __restrict__ Woe,
    const float* __restrict__ boe, const float* __restrict__ Wf,
    const float* __restrict__ bf, float* __restrict__ out)
{
    __shared__ float sH[HID];
    const int lig = blockIdx.x, tid = threadIdx.x;
    float s = 0.0f;
    const float* base = hh + (size_t)lig*KAT*HID + tid;
    #pragma unroll 8
    for (int a = 0; a < KAT; ++a) s += base[a*HID];
    sH[tid] = s * (1.0f/KAT);
    __syncthreads();

    float contrib = 0.0f;
    if (tid < OUTF) {
        float p = boe[tid];
        #pragma unroll 4
        for (int i = 0; i < HID; ++i)
            p = fmaf(sH[i], Woe[i*OUTF + tid], p);
        contrib = p * Wf[tid];
    }
    #pragma unroll
    for (int m = 1; m < 64; m <<= 1) contrib += __shfl_xor(contrib, m);
    if (tid == 0) out[lig] = contrib + bf[0];
}

// ---------------------------------------------------------------- launch
extern "C" void kernel_launch(void* const* d_in, const int* in_sizes, int n_in,
                              void* d_out, int out_size, void* d_ws, size_t ws_size,
                              hipStream_t stream)
{
    (void)in_sizes; (void)n_in; (void)out_size; (void)ws_size;
    const float* x    = (const float*)d_in[0];
    const float* h    = (const float*)d_in[1];
    const int*   t    = (const int*)d_in[2];
    const int*   edges= (const int*)d_in[3];
    const int*   tb   = (const int*)d_in[4];
    const float* temb = (const float*)d_in[8];
    const float* Win  = (const float*)d_in[9];
    const float* bin  = (const float*)d_in[10];
    const float* We1  = (const float*)d_in[11];
    const float* be1  = (const float*)d_in[12];
    const float* g1   = (const float*)d_in[13];
    const float* bt1  = (const float*)d_in[14];
    const float* We2  = (const float*)d_in[15];
    const float* be2  = (const float*)d_in[16];
    const float* Watt = (const float*)d_in[17];
    const float* batt = (const float*)d_in[18];
    const float* Wn1  = (const float*)d_in[19];
    const float* bn1  = (const float*)d_in[20];
    const float* g2   = (const float*)d_in[21];
    const float* bt2  = (const float*)d_in[22];
    const float* Wn2  = (const float*)d_in[23];
    const float* bn2  = (const float*)d_in[24];
    const float* Woe  = (const float*)d_in[25];
    const float* boe  = (const float*)d_in[26];
    const float* Wf   = (const float*)d_in[27];
    const float* bf   = (const float*)d_in[28];
    float* out = (float*)d_out;

    char* wsb = (char*)d_ws;
    float* hh  = (float*)(wsb);                        // 16 MB
    f16* hhF   = (f16*)(wsb + ((size_t)16<<20));       // 8 MB
    f16* tailG = (f16*)(wsb + ((size_t)24<<20));       // 2048*8192 f16 = 32 MB
    f16* tembF = (f16*)(wsb + ((size_t)58<<20));
    f16* W1T   = tembF + PREP_TEMB;
    f16* W2T   = W1T + PREP_W1;
    f16* WN1T  = W2T + PREP_W2;
    f16* WN2T  = WN1T + PREP_WN1;

    prep_k<<<(PREP_TOT + 255)/256, 256, 0, stream>>>(
        temb, We1, We2, Wn1, Wn2, tembF, W1T, W2T, WN1T, WN2T);

    tailprep_k<<<NNODES/NPB, 256, 0, stream>>>(
        x, edges + NEDGES, tb, tembF, tailG);

    embed_k<<<NNODES/8, 256, 0, stream>>>(h, t, temb, Win, bin, hh, hhF);

    for (int l = 0; l < 4; ++l) {
        fused_k<<<NNODES/NPB, 256, 0, stream>>>(
            hh, hhF, edges + NEDGES, tailG,
            W1T + (size_t)l*128*K1, W2T + (size_t)l*128*128,
            WN1T + (size_t)l*128*256, WN2T + (size_t)l*128*128,
            be1 + l*HID, g1 + l*HID, bt1 + l*HID, be2 + l*HID,
            Watt + l*HID, batt + l,
            bn1 + l*HID, g2 + l*HID, bt2 + l*HID, bn2 + l*HID);
    }
    out_k<<<NLIG, HID, 0, stream>>>(hh, Woe, boe, Wf, bf, out);
}